// Round 1
// baseline (5003.288 us; speedup 1.0000x reference)
//
#include <hip/hip_runtime.h>
#include <hip/hip_bf16.h>
#include <math.h>

// Problem constants (fixed by the reference)
#define N_NODES 50000
#define N_EDGES 800000
#define DIM     128
#define SDIM    64
#define SH_DIM  16
#define EA_DIM  32
#define FC_DIM  128
#define H_HEADS 8
#define AIN_DIM 160   // 2*SD + EA
#define LN_EPS  1e-5f

// Workspace layout (floats):
//   agg   : [0, N*D)                      = 6,400,000
//   cmax  : [N*D, N*D+8)   (as uint32)    monotone-mapped per-head max
//   csum  : [N*D+8, N*D+16)               per-head exp-sum
//   a_buf : [N*D+16, N*D+16+E*8)          attention logits
// total = 51,200,064 bytes (~48.8 MiB)

__device__ __forceinline__ float silu(float x) { return x / (1.0f + __expf(-x)); }

// monotone float <-> uint map so atomicMax(uint) implements float max (handles negatives)
__device__ __forceinline__ unsigned int fmap(float f) {
    unsigned int b = __float_as_uint(f);
    return (b & 0x80000000u) ? ~b : (b | 0x80000000u);
}
__device__ __forceinline__ float funmap(unsigned int u) {
    return (u & 0x80000000u) ? __uint_as_float(u & 0x7FFFFFFFu) : __uint_as_float(~u);
}

__global__ void k0_init(float* __restrict__ agg, unsigned int* __restrict__ cmax,
                        float* __restrict__ csum)
{
    const size_t total = (size_t)N_NODES * DIM;
    for (size_t i = (size_t)blockIdx.x * blockDim.x + threadIdx.x; i < total;
         i += (size_t)gridDim.x * blockDim.x)
        agg[i] = 0.0f;
    if (blockIdx.x == 0 && threadIdx.x < H_HEADS) {
        cmax[threadIdx.x] = fmap(-3.0e38f);
        csum[threadIdx.x] = 0.0f;
    }
}

// ---------------------------------------------------------------------------
// K1: attention logits a[E,8] = MLP([x_src[:,:64], x_dst[:,:64], edge_attr])
// 64 edges per block, 256 threads. Weights streamed from L1/L2 (not staged).
// ---------------------------------------------------------------------------
#define K1_EB 64

__global__ __launch_bounds__(256, 2) void k1_logits(
    const float* __restrict__ nodef, const float* __restrict__ eattr,
    const float* __restrict__ aW1, const float* __restrict__ ab1,
    const float* __restrict__ aW2, const float* __restrict__ ab2,
    const float* __restrict__ aW3, const float* __restrict__ ab3,
    const int* __restrict__ srcp, const int* __restrict__ dstp,
    float* __restrict__ a_out, unsigned int* __restrict__ cmax)
{
    __shared__ float ain[K1_EB * 164];   // alpha_in [64][160] (stride 164); reused as g2 [64][132]
    __shared__ float g1[K1_EB * 132];
    __shared__ int   sid[K1_EB];
    __shared__ int   did[K1_EB];
    __shared__ float aval[K1_EB * 8];

    const int tid = threadIdx.x;
    const int e0  = blockIdx.x * K1_EB;

    if (tid < K1_EB)            sid[tid]          = srcp[e0 + tid];
    else if (tid < 2 * K1_EB)   did[tid - K1_EB]  = dstp[e0 + tid - K1_EB];
    __syncthreads();

    // stage alpha_in as float4: per edge 40 float4 (16 src + 16 dst + 8 attr)
    for (int idx = tid; idx < K1_EB * 40; idx += 256) {
        int e = idx / 40, q = idx - e * 40;
        float4 v;
        if (q < 16)      v = ((const float4*)(nodef + (size_t)sid[e] * DIM))[q];
        else if (q < 32) v = ((const float4*)(nodef + (size_t)did[e] * DIM))[q - 16];
        else             v = ((const float4*)(eattr + (size_t)(e0 + e) * EA_DIM))[q - 32];
        *(float4*)(ain + e * 164 + q * 4) = v;
    }
    __syncthreads();

    const int tx = tid & 15;   // feature octet: f = tx*8 + i
    const int ty = tid >> 4;   // edge quad:     e = ty*4 + j
    float acc[4][8];

    // ---- layer 1: g1 = silu(alpha_in @ aW1 + ab1), K=160
    {
        float4 blo = ((const float4*)(ab1 + tx * 8))[0];
        float4 bhi = ((const float4*)(ab1 + tx * 8))[1];
        #pragma unroll
        for (int j = 0; j < 4; ++j) {
            acc[j][0] = blo.x; acc[j][1] = blo.y; acc[j][2] = blo.z; acc[j][3] = blo.w;
            acc[j][4] = bhi.x; acc[j][5] = bhi.y; acc[j][6] = bhi.z; acc[j][7] = bhi.w;
        }
        #pragma unroll 4
        for (int k = 0; k < AIN_DIM; ++k) {
            const float4 w0 = ((const float4*)(aW1 + (size_t)k * FC_DIM + tx * 8))[0];
            const float4 w1 = ((const float4*)(aW1 + (size_t)k * FC_DIM + tx * 8))[1];
            float av[4];
            #pragma unroll
            for (int j = 0; j < 4; ++j) av[j] = ain[(ty * 4 + j) * 164 + k];
            #pragma unroll
            for (int j = 0; j < 4; ++j) {
                acc[j][0] += av[j] * w0.x; acc[j][1] += av[j] * w0.y;
                acc[j][2] += av[j] * w0.z; acc[j][3] += av[j] * w0.w;
                acc[j][4] += av[j] * w1.x; acc[j][5] += av[j] * w1.y;
                acc[j][6] += av[j] * w1.z; acc[j][7] += av[j] * w1.w;
            }
        }
        #pragma unroll
        for (int j = 0; j < 4; ++j) {
            float4 lo = make_float4(silu(acc[j][0]), silu(acc[j][1]), silu(acc[j][2]), silu(acc[j][3]));
            float4 hi = make_float4(silu(acc[j][4]), silu(acc[j][5]), silu(acc[j][6]), silu(acc[j][7]));
            *(float4*)(g1 + (ty * 4 + j) * 132 + tx * 8)     = lo;
            *(float4*)(g1 + (ty * 4 + j) * 132 + tx * 8 + 4) = hi;
        }
    }
    __syncthreads();

    // ---- layer 2: g2 = silu(g1 @ aW2 + ab2), K=128 (g2 overwrites ain region)
    float* g2 = ain;
    {
        float4 blo = ((const float4*)(ab2 + tx * 8))[0];
        float4 bhi = ((const float4*)(ab2 + tx * 8))[1];
        #pragma unroll
        for (int j = 0; j < 4; ++j) {
            acc[j][0] = blo.x; acc[j][1] = blo.y; acc[j][2] = blo.z; acc[j][3] = blo.w;
            acc[j][4] = bhi.x; acc[j][5] = bhi.y; acc[j][6] = bhi.z; acc[j][7] = bhi.w;
        }
        #pragma unroll 4
        for (int k = 0; k < FC_DIM; ++k) {
            const float4 w0 = ((const float4*)(aW2 + (size_t)k * FC_DIM + tx * 8))[0];
            const float4 w1 = ((const float4*)(aW2 + (size_t)k * FC_DIM + tx * 8))[1];
            float av[4];
            #pragma unroll
            for (int j = 0; j < 4; ++j) av[j] = g1[(ty * 4 + j) * 132 + k];
            #pragma unroll
            for (int j = 0; j < 4; ++j) {
                acc[j][0] += av[j] * w0.x; acc[j][1] += av[j] * w0.y;
                acc[j][2] += av[j] * w0.z; acc[j][3] += av[j] * w0.w;
                acc[j][4] += av[j] * w1.x; acc[j][5] += av[j] * w1.y;
                acc[j][6] += av[j] * w1.z; acc[j][7] += av[j] * w1.w;
            }
        }
        __syncthreads();   // all layer-1 reads of ain done before overwrite
        #pragma unroll
        for (int j = 0; j < 4; ++j) {
            float4 lo = make_float4(silu(acc[j][0]), silu(acc[j][1]), silu(acc[j][2]), silu(acc[j][3]));
            float4 hi = make_float4(silu(acc[j][4]), silu(acc[j][5]), silu(acc[j][6]), silu(acc[j][7]));
            *(float4*)(g2 + (ty * 4 + j) * 132 + tx * 8)     = lo;
            *(float4*)(g2 + (ty * 4 + j) * 132 + tx * 8 + 4) = hi;
        }
    }
    __syncthreads();

    // ---- layer 3: a = g2 @ aW3 + ab3  (8 heads); remap: 4 threads per edge
    {
        const int e  = tid >> 2;
        const int hp = (tid & 3) * 2;
        float a0 = ab3[hp], a1 = ab3[hp + 1];
        #pragma unroll 8
        for (int k = 0; k < FC_DIM; ++k) {
            float  g = g2[e * 132 + k];
            float2 w = *((const float2*)(aW3 + (size_t)k * H_HEADS + hp));
            a0 += g * w.x; a1 += g * w.y;
        }
        a_out[(size_t)(e0 + e) * H_HEADS + hp]     = a0;
        a_out[(size_t)(e0 + e) * H_HEADS + hp + 1] = a1;
        aval[e * 8 + hp] = a0; aval[e * 8 + hp + 1] = a1;
    }
    __syncthreads();

    if (tid < H_HEADS) {
        float m = -3.0e38f;
        for (int e = 0; e < K1_EB; ++e) m = fmaxf(m, aval[e * 8 + tid]);
        atomicMax(&cmax[tid], fmap(m));
    }
}

// ---------------------------------------------------------------------------
// K2: per-head sum of exp(a - max) over all E edges
// ---------------------------------------------------------------------------
__global__ void k2_expsum(const float* __restrict__ a_buf,
                          const unsigned int* __restrict__ cmax,
                          float* __restrict__ csum)
{
    __shared__ float partial[4][8];
    const int tid = threadIdx.x;
    const int h   = tid & 7;
    const float M = funmap(cmax[h]);
    float s = 0.f;
    const int total = N_EDGES * H_HEADS;            // 6.4M
    const int stride = gridDim.x * 256;             // multiple of 8 -> h invariant
    for (int i = blockIdx.x * 256 + tid; i < total; i += stride)
        s += __expf(a_buf[i] - M);
    s += __shfl_xor(s, 8);
    s += __shfl_xor(s, 16);
    s += __shfl_xor(s, 32);
    const int wave = tid >> 6, lane = tid & 63;
    if (lane < 8) partial[wave][lane] = s;
    __syncthreads();
    if (tid < 8) {
        float t = partial[0][tid] + partial[1][tid] + partial[2][tid] + partial[3][tid];
        atomicAdd(&csum[tid], t);
    }
}

// ---------------------------------------------------------------------------
// K3: message path + alpha scaling + scatter-add into agg
// 32 edges per block, 256 threads.
// ---------------------------------------------------------------------------
#define K3_EB 32

__global__ __launch_bounds__(256, 2) void k3_message(
    const float* __restrict__ nodef, const float* __restrict__ eattr,
    const float* __restrict__ esh,
    const float* __restrict__ W_node,
    const float* __restrict__ fc1, const float* __restrict__ b1,
    const float* __restrict__ fc2, const float* __restrict__ b2,
    const float* __restrict__ fc3, const float* __restrict__ b3,
    const float* __restrict__ W_sh,
    const int* __restrict__ srcp, const int* __restrict__ dstp,
    const float* __restrict__ a_buf, const unsigned int* __restrict__ cmax,
    const float* __restrict__ csum,
    float* __restrict__ agg)
{
    __shared__ float eaL[K3_EB * 36];
    __shared__ float xsL[K3_EB * 132];
    __shared__ float shL[K3_EB * 20];
    __shared__ float h1L[K3_EB * 132];
    __shared__ float h2L[K3_EB * 132];
    __shared__ float amL[K3_EB];
    __shared__ int   sidL[K3_EB];
    __shared__ int   didL[K3_EB];

    const int tid = threadIdx.x;
    const int e0  = blockIdx.x * K3_EB;

    if (tid < K3_EB)            sidL[tid]         = srcp[e0 + tid];
    else if (tid < 2 * K3_EB)   didL[tid - K3_EB] = dstp[e0 + tid - K3_EB];
    __syncthreads();

    for (int idx = tid; idx < K3_EB * 8; idx += 256) {      // edge_attr
        int e = idx >> 3, q = idx & 7;
        *(float4*)(eaL + e * 36 + q * 4) = ((const float4*)(eattr + (size_t)(e0 + e) * EA_DIM))[q];
    }
    for (int idx = tid; idx < K3_EB * 4; idx += 256) {      // edge_sh
        int e = idx >> 2, q = idx & 3;
        *(float4*)(shL + e * 20 + q * 4) = ((const float4*)(esh + (size_t)(e0 + e) * SH_DIM))[q];
    }
    for (int idx = tid; idx < K3_EB * 32; idx += 256) {     // x_src gather
        int e = idx >> 5, q = idx & 31;
        *(float4*)(xsL + e * 132 + q * 4) = ((const float4*)(nodef + (size_t)sidL[e] * DIM))[q];
    }
    if (tid < K3_EB) {                                      // alpha_mean per edge
        float s = 0.f;
        #pragma unroll
        for (int h = 0; h < H_HEADS; ++h) {
            float M = funmap(cmax[h]);
            s += __expf(a_buf[(size_t)(e0 + tid) * H_HEADS + h] - M) / csum[h];
        }
        amL[tid] = s * (1.0f / H_HEADS);
    }
    __syncthreads();

    const int tx = tid & 15;   // f = tx*8 + i
    const int ty = tid >> 4;   // e = ty*2 + j
    float acc[2][8];

    // h1 = silu(ea @ fc1 + b1), K=32
    {
        float4 blo = ((const float4*)(b1 + tx * 8))[0];
        float4 bhi = ((const float4*)(b1 + tx * 8))[1];
        #pragma unroll
        for (int j = 0; j < 2; ++j) {
            acc[j][0] = blo.x; acc[j][1] = blo.y; acc[j][2] = blo.z; acc[j][3] = blo.w;
            acc[j][4] = bhi.x; acc[j][5] = bhi.y; acc[j][6] = bhi.z; acc[j][7] = bhi.w;
        }
        #pragma unroll 4
        for (int k = 0; k < EA_DIM; ++k) {
            const float4 w0 = ((const float4*)(fc1 + (size_t)k * FC_DIM + tx * 8))[0];
            const float4 w1 = ((const float4*)(fc1 + (size_t)k * FC_DIM + tx * 8))[1];
            float av[2];
            #pragma unroll
            for (int j = 0; j < 2; ++j) av[j] = eaL[(ty * 2 + j) * 36 + k];
            #pragma unroll
            for (int j = 0; j < 2; ++j) {
                acc[j][0] += av[j] * w0.x; acc[j][1] += av[j] * w0.y;
                acc[j][2] += av[j] * w0.z; acc[j][3] += av[j] * w0.w;
                acc[j][4] += av[j] * w1.x; acc[j][5] += av[j] * w1.y;
                acc[j][6] += av[j] * w1.z; acc[j][7] += av[j] * w1.w;
            }
        }
        #pragma unroll
        for (int j = 0; j < 2; ++j) {
            float4 lo = make_float4(silu(acc[j][0]), silu(acc[j][1]), silu(acc[j][2]), silu(acc[j][3]));
            float4 hi = make_float4(silu(acc[j][4]), silu(acc[j][5]), silu(acc[j][6]), silu(acc[j][7]));
            *(float4*)(h1L + (ty * 2 + j) * 132 + tx * 8)     = lo;
            *(float4*)(h1L + (ty * 2 + j) * 132 + tx * 8 + 4) = hi;
        }
    }
    __syncthreads();

    // h2 = silu(h1 @ fc2 + b2), K=128
    {
        float4 blo = ((const float4*)(b2 + tx * 8))[0];
        float4 bhi = ((const float4*)(b2 + tx * 8))[1];
        #pragma unroll
        for (int j = 0; j < 2; ++j) {
            acc[j][0] = blo.x; acc[j][1] = blo.y; acc[j][2] = blo.z; acc[j][3] = blo.w;
            acc[j][4] = bhi.x; acc[j][5] = bhi.y; acc[j][6] = bhi.z; acc[j][7] = bhi.w;
        }
        #pragma unroll 4
        for (int k = 0; k < FC_DIM; ++k) {
            const float4 w0 = ((const float4*)(fc2 + (size_t)k * FC_DIM + tx * 8))[0];
            const float4 w1 = ((const float4*)(fc2 + (size_t)k * FC_DIM + tx * 8))[1];
            float av[2];
            #pragma unroll
            for (int j = 0; j < 2; ++j) av[j] = h1L[(ty * 2 + j) * 132 + k];
            #pragma unroll
            for (int j = 0; j < 2; ++j) {
                acc[j][0] += av[j] * w0.x; acc[j][1] += av[j] * w0.y;
                acc[j][2] += av[j] * w0.z; acc[j][3] += av[j] * w0.w;
                acc[j][4] += av[j] * w1.x; acc[j][5] += av[j] * w1.y;
                acc[j][6] += av[j] * w1.z; acc[j][7] += av[j] * w1.w;
            }
        }
        #pragma unroll
        for (int j = 0; j < 2; ++j) {
            float4 lo = make_float4(silu(acc[j][0]), silu(acc[j][1]), silu(acc[j][2]), silu(acc[j][3]));
            float4 hi = make_float4(silu(acc[j][4]), silu(acc[j][5]), silu(acc[j][6]), silu(acc[j][7]));
            *(float4*)(h2L + (ty * 2 + j) * 132 + tx * 8)     = lo;
            *(float4*)(h2L + (ty * 2 + j) * 132 + tx * 8 + 4) = hi;
        }
    }
    __syncthreads();

    // scale = h2 @ fc3 + b3 ; xw = x_src @ W_node ; sw = edge_sh @ W_sh
    float sc[2][8], xw[2][8], sw[2][8];
    {
        float4 blo = ((const float4*)(b3 + tx * 8))[0];
        float4 bhi = ((const float4*)(b3 + tx * 8))[1];
        #pragma unroll
        for (int j = 0; j < 2; ++j) {
            sc[j][0] = blo.x; sc[j][1] = blo.y; sc[j][2] = blo.z; sc[j][3] = blo.w;
            sc[j][4] = bhi.x; sc[j][5] = bhi.y; sc[j][6] = bhi.z; sc[j][7] = bhi.w;
            #pragma unroll
            for (int i = 0; i < 8; ++i) { xw[j][i] = 0.f; sw[j][i] = 0.f; }
        }
        #pragma unroll 4
        for (int k = 0; k < FC_DIM; ++k) {
            const float4 w0 = ((const float4*)(fc3 + (size_t)k * FC_DIM + tx * 8))[0];
            const float4 w1 = ((const float4*)(fc3 + (size_t)k * FC_DIM + tx * 8))[1];
            float av[2];
            #pragma unroll
            for (int j = 0; j < 2; ++j) av[j] = h2L[(ty * 2 + j) * 132 + k];
            #pragma unroll
            for (int j = 0; j < 2; ++j) {
                sc[j][0] += av[j] * w0.x; sc[j][1] += av[j] * w0.y;
                sc[j][2] += av[j] * w0.z; sc[j][3] += av[j] * w0.w;
                sc[j][4] += av[j] * w1.x; sc[j][5] += av[j] * w1.y;
                sc[j][6] += av[j] * w1.z; sc[j][7] += av[j] * w1.w;
            }
        }
        #pragma unroll 4
        for (int k = 0; k < DIM; ++k) {
            const float4 w0 = ((const float4*)(W_node + (size_t)k * DIM + tx * 8))[0];
            const float4 w1 = ((const float4*)(W_node + (size_t)k * DIM + tx * 8))[1];
            float av[2];
            #pragma unroll
            for (int j = 0; j < 2; ++j) av[j] = xsL[(ty * 2 + j) * 132 + k];
            #pragma unroll
            for (int j = 0; j < 2; ++j) {
                xw[j][0] += av[j] * w0.x; xw[j][1] += av[j] * w0.y;
                xw[j][2] += av[j] * w0.z; xw[j][3] += av[j] * w0.w;
                xw[j][4] += av[j] * w1.x; xw[j][5] += av[j] * w1.y;
                xw[j][6] += av[j] * w1.z; xw[j][7] += av[j] * w1.w;
            }
        }
        #pragma unroll
        for (int k = 0; k < SH_DIM; ++k) {
            const float4 w0 = ((const float4*)(W_sh + (size_t)k * DIM + tx * 8))[0];
            const float4 w1 = ((const float4*)(W_sh + (size_t)k * DIM + tx * 8))[1];
            float av[2];
            #pragma unroll
            for (int j = 0; j < 2; ++j) av[j] = shL[(ty * 2 + j) * 20 + k];
            #pragma unroll
            for (int j = 0; j < 2; ++j) {
                sw[j][0] += av[j] * w0.x; sw[j][1] += av[j] * w0.y;
                sw[j][2] += av[j] * w0.z; sw[j][3] += av[j] * w0.w;
                sw[j][4] += av[j] * w1.x; sw[j][5] += av[j] * w1.y;
                sw[j][6] += av[j] * w1.z; sw[j][7] += av[j] * w1.w;
            }
        }
    }

    // msg = silu(xw*scale + sw) * alpha_mean, scatter-add into agg[dst]
    #pragma unroll
    for (int j = 0; j < 2; ++j) {
        const int e = ty * 2 + j;
        const float am = amL[e];
        float* arow = agg + (size_t)didL[e] * DIM + tx * 8;
        #pragma unroll
        for (int i = 0; i < 8; ++i) {
            float m = silu(xw[j][i] * sc[j][i] + sw[j][i]);
            atomicAdd(arow + i, m * am);
        }
    }
}

// ---------------------------------------------------------------------------
// K4: out = LayerNorm(node_features + agg @ W_out)    (16 nodes per block)
// ---------------------------------------------------------------------------
#define K4_NB 16

__global__ __launch_bounds__(256, 2) void k4_out(
    const float* __restrict__ nodef, const float* __restrict__ agg,
    const float* __restrict__ W_out, float* __restrict__ outp)
{
    __shared__ float aggL[K4_NB * 132];
    __shared__ float outL[K4_NB * 144];
    const int tid = threadIdx.x;
    const int n0  = blockIdx.x * K4_NB;

    for (int idx = tid; idx < K4_NB * 32; idx += 256) {
        int nl = idx >> 5, q = idx & 31;
        *(float4*)(aggL + nl * 132 + q * 4) = ((const float4*)(agg + (size_t)(n0 + nl) * DIM))[q];
    }
    __syncthreads();

    const int f = tid & 127, ng = tid >> 7;  // 2 groups x 8 nodes
    float acc[8];
    #pragma unroll
    for (int j = 0; j < 8; ++j) acc[j] = nodef[(size_t)(n0 + ng * 8 + j) * DIM + f];
    #pragma unroll 4
    for (int k = 0; k < DIM; ++k) {
        const float w = W_out[(size_t)k * DIM + f];
        #pragma unroll
        for (int j = 0; j < 8; ++j) acc[j] += aggL[(ng * 8 + j) * 132 + k] * w;
    }
    #pragma unroll
    for (int j = 0; j < 8; ++j) outL[(ng * 8 + j) * 144 + f] = acc[j];
    __syncthreads();

    // LayerNorm: 16 threads per node (within-wave shuffle reduce)
    const int node = tid >> 4, l16 = tid & 15;
    float v[8];
    float s = 0.f;
    #pragma unroll
    for (int j = 0; j < 8; ++j) { v[j] = outL[node * 144 + l16 + j * 16]; s += v[j]; }
    #pragma unroll
    for (int m = 1; m < 16; m <<= 1) s += __shfl_xor(s, m);
    const float mu = s * (1.0f / DIM);
    float vs = 0.f;
    #pragma unroll
    for (int j = 0; j < 8; ++j) { float d = v[j] - mu; vs += d * d; }
    #pragma unroll
    for (int m = 1; m < 16; m <<= 1) vs += __shfl_xor(vs, m);
    const float rstd = rsqrtf(vs * (1.0f / DIM) + LN_EPS);
    #pragma unroll
    for (int j = 0; j < 8; ++j)
        outp[(size_t)(n0 + node) * DIM + l16 + j * 16] = (v[j] - mu) * rstd;
}

// ---------------------------------------------------------------------------
extern "C" void kernel_launch(void* const* d_in, const int* in_sizes, int n_in,
                              void* d_out, int out_size, void* d_ws, size_t ws_size,
                              hipStream_t stream)
{
    const float* nodef  = (const float*)d_in[0];
    const float* eattr  = (const float*)d_in[1];
    const float* esh    = (const float*)d_in[2];
    const float* W_node = (const float*)d_in[3];
    const float* fc1    = (const float*)d_in[4];
    const float* b1     = (const float*)d_in[5];
    const float* fc2    = (const float*)d_in[6];
    const float* b2     = (const float*)d_in[7];
    const float* fc3    = (const float*)d_in[8];
    const float* b3     = (const float*)d_in[9];
    const float* W_sh   = (const float*)d_in[10];
    const float* aW1    = (const float*)d_in[11];
    const float* ab1    = (const float*)d_in[12];
    const float* aW2    = (const float*)d_in[13];
    const float* ab2    = (const float*)d_in[14];
    const float* aW3    = (const float*)d_in[15];
    const float* ab3    = (const float*)d_in[16];
    const float* W_out  = (const float*)d_in[17];
    const int*   eidx   = (const int*)d_in[18];
    // d_in[19] = batch (unused: reference never uses it)
    const int* srcp = eidx;
    const int* dstp = eidx + N_EDGES;

    float* ws   = (float*)d_ws;
    float* agg  = ws;                                        // N*D
    unsigned int* cmax = (unsigned int*)(ws + (size_t)N_NODES * DIM);
    float* csum = ws + (size_t)N_NODES * DIM + 8;
    float* a_buf = ws + (size_t)N_NODES * DIM + 16;          // E*H
    float* outp = (float*)d_out;

    k0_init   <<<2048, 256, 0, stream>>>(agg, cmax, csum);
    k1_logits <<<N_EDGES / K1_EB, 256, 0, stream>>>(nodef, eattr, aW1, ab1, aW2, ab2,
                                                    aW3, ab3, srcp, dstp, a_buf, cmax);
    k2_expsum <<<1024, 256, 0, stream>>>(a_buf, cmax, csum);
    k3_message<<<N_EDGES / K3_EB, 256, 0, stream>>>(nodef, eattr, esh, W_node,
                                                    fc1, b1, fc2, b2, fc3, b3, W_sh,
                                                    srcp, dstp, a_buf, cmax, csum, agg);
    k4_out    <<<N_NODES / K4_NB, 256, 0, stream>>>(nodef, agg, W_out, outp);
}

// Round 2
// 1149.510 us; speedup vs baseline: 4.3525x; 4.3525x over previous
//
#include <hip/hip_runtime.h>
#include <math.h>

// Problem constants (fixed by the reference)
#define N_NODES 50000
#define N_EDGES 800000
#define DIM     128
#define SDIM    64
#define SH_DIM  16
#define EA_DIM  32
#define FC_DIM  128
#define H_HEADS 8
#define AIN_DIM 160   // 2*SD + EA
#define LN_EPS  1e-5f

typedef __attribute__((ext_vector_type(8))) short short8;   // 8 bf16 = one MFMA A/B fragment
typedef __attribute__((ext_vector_type(4))) short short4v;
typedef __attribute__((ext_vector_type(4))) float f32x4;

// Weight-fragment buffer layout (units of short8 = 16B fragments)
#define FR_FC1 0       // K=32  -> 1*8*64
#define FR_FC2 512     // K=128 -> 4*8*64
#define FR_FC3 2560
#define FR_WND 4608
#define FR_WSH 6656    // K=16 padded to 32
#define FR_AW1 7168    // K=160 -> 5*8*64
#define FR_AW2 9728
#define FR_AW3 11776   // K=128, N=8 (1 col tile) -> 4*1*64
#define FR_TOTAL 12032

// ws layout (floats):
//   aggB (bf16[N][128])  : [0, 3,200,000)        (N*64 floats worth of bytes)
//   cmax (8 uint)        : [3,200,000, 3,200,008)
//   csum (8 f32)         : [3,200,008, 3,200,016)
//   a_buf (f32[E][8])    : [3,200,016, 9,600,016)
//   frags (bf16 frags)   : [9,600,016, +48,128)   16B-aligned
// total ~38.6 MB

__device__ __forceinline__ float silu(float x) { return x / (1.0f + __expf(-x)); }

__device__ __forceinline__ unsigned short f2bf(float x) {     // RNE fp32->bf16
    unsigned u = __float_as_uint(x);
    return (unsigned short)((u + 0x7FFFu + ((u >> 16) & 1u)) >> 16);
}
__device__ __forceinline__ float bf2f(unsigned short h) { return __uint_as_float(((unsigned)h) << 16); }

__device__ __forceinline__ unsigned int fmap(float f) {
    unsigned int b = __float_as_uint(f);
    return (b & 0x80000000u) ? ~b : (b | 0x80000000u);
}
__device__ __forceinline__ float funmap(unsigned int u) {
    return (u & 0x80000000u) ? __uint_as_float(u & 0x7FFFFFFFu) : __uint_as_float(~u);
}

// ---------------------------------------------------------------------------
// mm_acc: per-wave MFMA GEMM over a 16-row LDS activation tile.
// A-frag: lane reads act[rowBase + (lane&15)][ks*32 + (lane>>4)*8 .. +7] (bf16,
// XOR-swizzled). B-frag: fragment-linear bf16 weights in global (L2-hot).
// ---------------------------------------------------------------------------
template<int KSTEPS, int NT, int STRIDE>
__device__ __forceinline__ void mm_acc(const char* aBase, int rowBase, int lane,
                                       const short8* __restrict__ bfrag, f32x4* acc)
{
    const int row  = rowBase + (lane & 15);
    const int swz  = (row & 7) << 4;
    const int rb   = row * STRIDE;
    const int koff = (lane >> 4) << 4;
    #pragma unroll
    for (int ks = 0; ks < KSTEPS; ++ks) {
        short8 a = *(const short8*)(aBase + ((rb + ks * 64 + koff) ^ swz));
        #pragma unroll
        for (int ct = 0; ct < NT; ++ct) {
            short8 b = bfrag[(ks * NT + ct) * 64 + lane];
            acc[ct] = __builtin_amdgcn_mfma_f32_16x16x32_bf16(a, b, acc[ct], 0, 0, 0);
        }
    }
}

// Store 8 col-tiles of a D-tile (col=lane&15, row=(lane>>4)*4+r) to swizzled
// bf16 LDS, adding bias and applying silu.
template<int STRIDE>
__device__ __forceinline__ void store_rows_silu(char* base, int rowBase, int lane,
                                                const f32x4* acc, const float* __restrict__ bias)
{
    const int l15  = lane & 15;
    const int col2 = l15 * 2;
    #pragma unroll
    for (int ct = 0; ct < 8; ++ct) {
        const float bv = bias[ct * 16 + l15];
        #pragma unroll
        for (int r = 0; r < 4; ++r) {
            const int row = rowBase + ((lane >> 4) * 4) + r;
            const float v = silu(acc[ct][r] + bv);
            const int off = (row * STRIDE + ct * 32 + col2) ^ ((row & 7) << 4);
            *(short*)(base + off) = (short)f2bf(v);
        }
    }
}

__device__ __forceinline__ void zero8(f32x4* a) {
    #pragma unroll
    for (int i = 0; i < 8; ++i) a[i] = (f32x4){0.f, 0.f, 0.f, 0.f};
}

// ---------------------------------------------------------------------------
// k_prep: convert all weight matrices to transposed bf16 fragment layout.
// frag[(ks*NT+ct)*64 + lane][i] = W[ks*32 + (lane>>4)*8 + i][ct*16 + (lane&15)]
// (zero-padded past Ksrc/Nsrc). 12032 fragments total -> 47 blocks x 256.
// ---------------------------------------------------------------------------
__global__ void k_prep(const float* __restrict__ fc1, const float* __restrict__ fc2,
                       const float* __restrict__ fc3, const float* __restrict__ W_node,
                       const float* __restrict__ W_sh, const float* __restrict__ aW1,
                       const float* __restrict__ aW2, const float* __restrict__ aW3,
                       short8* __restrict__ frags)
{
    const int gid = blockIdx.x * 256 + threadIdx.x;   // exactly 12032 threads
    const float* src; int Ksrc, Nsrc, Nld, NT, base;
    if (gid < 2560) {
        if (gid < 512)  { src = fc1;  Ksrc = 32;  Nsrc = 128; Nld = 128; NT = 8; base = FR_FC1; }
        else            { src = fc2;  Ksrc = 128; Nsrc = 128; Nld = 128; NT = 8; base = FR_FC2; }
    } else if (gid < 6656) {
        if (gid < 4608) { src = fc3;    Ksrc = 128; Nsrc = 128; Nld = 128; NT = 8; base = FR_FC3; }
        else            { src = W_node; Ksrc = 128; Nsrc = 128; Nld = 128; NT = 8; base = FR_WND; }
    } else if (gid < 9728) {
        if (gid < 7168) { src = W_sh; Ksrc = 16;  Nsrc = 128; Nld = 128; NT = 8; base = FR_WSH; }
        else            { src = aW1;  Ksrc = 160; Nsrc = 128; Nld = 128; NT = 8; base = FR_AW1; }
    } else {
        if (gid < 11776){ src = aW2;  Ksrc = 128; Nsrc = 128; Nld = 128; NT = 8; base = FR_AW2; }
        else            { src = aW3;  Ksrc = 128; Nsrc = 8;   Nld = 8;   NT = 1; base = FR_AW3; }
    }
    const int local = gid - base;
    const int lane = local & 63;
    const int tmp  = local >> 6;
    const int ct   = tmp % NT;
    const int ks   = tmp / NT;
    const int col  = ct * 16 + (lane & 15);
    const int k0   = ks * 32 + ((lane >> 4) << 3);
    unsigned short o[8];
    #pragma unroll
    for (int i = 0; i < 8; ++i) {
        const int k = k0 + i;
        const float v = (k < Ksrc && col < Nsrc) ? src[(size_t)k * Nld + col] : 0.f;
        o[i] = f2bf(v);
    }
    unsigned a = (unsigned)o[0] | ((unsigned)o[1] << 16);
    unsigned b = (unsigned)o[2] | ((unsigned)o[3] << 16);
    unsigned c = (unsigned)o[4] | ((unsigned)o[5] << 16);
    unsigned d = (unsigned)o[6] | ((unsigned)o[7] << 16);
    ((uint4*)frags)[gid] = make_uint4(a, b, c, d);
}

__global__ void k0_init(float* __restrict__ aggz, unsigned int* __restrict__ cmax,
                        float* __restrict__ csum)
{
    const int total = N_NODES * (DIM / 2);   // bf16 agg = 3.2M dwords
    for (int i = blockIdx.x * blockDim.x + threadIdx.x; i < total;
         i += gridDim.x * blockDim.x)
        aggz[i] = 0.0f;
    if (blockIdx.x == 0 && threadIdx.x < H_HEADS) {
        cmax[threadIdx.x] = fmap(-3.0e38f);
        csum[threadIdx.x] = 0.0f;
    }
}

// ---------------------------------------------------------------------------
// K1: attention logits via MFMA. 64 edges/block, 4 waves x 16 edges.
// ---------------------------------------------------------------------------
__global__ __launch_bounds__(256, 2) void k1_logits(
    const float* __restrict__ nodef, const float* __restrict__ eattr,
    const float* __restrict__ ab1, const float* __restrict__ ab2,
    const float* __restrict__ ab3,
    const short8* __restrict__ frags,
    const int* __restrict__ srcp, const int* __restrict__ dstp,
    float* __restrict__ a_out, unsigned int* __restrict__ cmax)
{
    __shared__ __align__(16) char sAIN[64 * 512];   // [64][160->pad256] bf16, swizzled
    __shared__ __align__(16) char sG1[64 * 256];
    __shared__ __align__(16) char sG2[64 * 256];
    __shared__ int sid[64], did[64];
    __shared__ float wmaxL[32];

    const int tid = threadIdx.x;
    const int e0  = blockIdx.x * 64;

    if (tid < 64)            sid[tid]      = srcp[e0 + tid];
    else if (tid < 128)      did[tid - 64] = dstp[e0 + tid - 64];
    __syncthreads();

    // stage alpha_in = [x_src[:64], x_dst[:64], edge_attr] as bf16, swizzled
    for (int idx = tid; idx < 64 * 40; idx += 256) {
        const int e = idx / 40, q = idx - e * 40;
        float4 v; int k;
        if (q < 16)      { v = ((const float4*)(nodef + (size_t)sid[e] * DIM))[q];      k = q * 4; }
        else if (q < 32) { v = ((const float4*)(nodef + (size_t)did[e] * DIM))[q - 16]; k = 64 + (q - 16) * 4; }
        else             { v = ((const float4*)(eattr + (size_t)(e0 + e) * EA_DIM))[q - 32]; k = 128 + (q - 32) * 4; }
        short4v h = {(short)f2bf(v.x), (short)f2bf(v.y), (short)f2bf(v.z), (short)f2bf(v.w)};
        *(short4v*)(sAIN + ((e * 512 + k * 2) ^ ((e & 7) << 4))) = h;
    }
    __syncthreads();

    const int lane = tid & 63, w = tid >> 6;
    const int rowBase = w * 16;
    f32x4 g[8];

    zero8(g);
    mm_acc<5, 8, 512>(sAIN, rowBase, lane, frags + FR_AW1, g);
    store_rows_silu<256>(sG1, rowBase, lane, g, ab1);

    zero8(g);
    mm_acc<4, 8, 256>(sG1, rowBase, lane, frags + FR_AW2, g);
    store_rows_silu<256>(sG2, rowBase, lane, g, ab2);

    f32x4 p = {0.f, 0.f, 0.f, 0.f};
    mm_acc<4, 1, 256>(sG2, rowBase, lane, frags + FR_AW3, &p);

    const int h = lane & 15;
    float vmax = -3.0e38f;
    if (h < H_HEADS) {
        const float ab = ab3[h];
        #pragma unroll
        for (int r = 0; r < 4; ++r) {
            const int row = rowBase + ((lane >> 4) * 4) + r;
            const float v = p[r] + ab;
            a_out[(size_t)(e0 + row) * H_HEADS + h] = v;
            vmax = fmaxf(vmax, v);
        }
    }
    vmax = fmaxf(vmax, __shfl_xor(vmax, 16));
    vmax = fmaxf(vmax, __shfl_xor(vmax, 32));
    if (lane < 8) wmaxL[w * 8 + lane] = vmax;
    __syncthreads();
    if (tid < 8) {
        const float m = fmaxf(fmaxf(wmaxL[tid], wmaxL[8 + tid]),
                              fmaxf(wmaxL[16 + tid], wmaxL[24 + tid]));
        atomicMax(&cmax[tid], fmap(m));
    }
}

// ---------------------------------------------------------------------------
// K2: per-head sum of exp(a - max)
// ---------------------------------------------------------------------------
__global__ void k2_expsum(const float* __restrict__ a_buf,
                          const unsigned int* __restrict__ cmax,
                          float* __restrict__ csum)
{
    __shared__ float partial[4][8];
    const int tid = threadIdx.x;
    const int h   = tid & 7;
    const float M = funmap(cmax[h]);
    float s = 0.f;
    const int total = N_EDGES * H_HEADS;
    const int stride = gridDim.x * 256;
    for (int i = blockIdx.x * 256 + tid; i < total; i += stride)
        s += __expf(a_buf[i] - M);
    s += __shfl_xor(s, 8);
    s += __shfl_xor(s, 16);
    s += __shfl_xor(s, 32);
    const int wave = tid >> 6, lane = tid & 63;
    if (lane < 8) partial[wave][lane] = s;
    __syncthreads();
    if (tid < 8) {
        float t = partial[0][tid] + partial[1][tid] + partial[2][tid] + partial[3][tid];
        atomicAdd(&csum[tid], t);
    }
}

// ---------------------------------------------------------------------------
// K3: message path via MFMA + packed-bf16 scatter atomics.
// 64 edges/block, 4 waves x 16 edges.
// ---------------------------------------------------------------------------
__global__ __launch_bounds__(256, 2) void k3_message(
    const float* __restrict__ nodef, const float* __restrict__ eattr,
    const float* __restrict__ esh,
    const float* __restrict__ b1, const float* __restrict__ b2,
    const float* __restrict__ b3,
    const short8* __restrict__ frags,
    const int* __restrict__ srcp, const int* __restrict__ dstp,
    const float* __restrict__ a_buf, const unsigned int* __restrict__ cmax,
    const float* __restrict__ csum,
    unsigned short* __restrict__ aggB)
{
    __shared__ __align__(16) char sEA[64 * 128];    // [64][32->pad64] bf16
    __shared__ __align__(16) char sSH[64 * 128];    // [64][16->pad32, zeroed] bf16
    __shared__ __align__(16) char sXS[64 * 256];    // [64][128] bf16
    __shared__ __align__(16) char sH1[64 * 256];
    __shared__ __align__(16) char sH2[64 * 256];
    __shared__ float amL[64];
    __shared__ int sidL[64], didL[64];

    const int tid = threadIdx.x;
    const int e0  = blockIdx.x * 64;

    if (tid < 64)       sidL[tid]      = srcp[e0 + tid];
    else if (tid < 128) didL[tid - 64] = dstp[e0 + tid - 64];
    __syncthreads();

    for (int idx = tid; idx < 64 * 32; idx += 256) {        // x_src
        const int e = idx >> 5, q = idx & 31;
        float4 v = ((const float4*)(nodef + (size_t)sidL[e] * DIM))[q];
        short4v h = {(short)f2bf(v.x), (short)f2bf(v.y), (short)f2bf(v.z), (short)f2bf(v.w)};
        *(short4v*)(sXS + ((e * 256 + q * 8) ^ ((e & 7) << 4))) = h;
    }
    for (int idx = tid; idx < 64 * 8; idx += 256) {         // edge_attr
        const int e = idx >> 3, q = idx & 7;
        float4 v = ((const float4*)(eattr + (size_t)(e0 + e) * EA_DIM))[q];
        short4v h = {(short)f2bf(v.x), (short)f2bf(v.y), (short)f2bf(v.z), (short)f2bf(v.w)};
        *(short4v*)(sEA + ((e * 128 + q * 8) ^ ((e & 7) << 4))) = h;
    }
    for (int idx = tid; idx < 64 * 8; idx += 256) {         // edge_sh (zero-padded K 16->32)
        const int e = idx >> 3, q = idx & 7;
        short4v h = {0, 0, 0, 0};
        if (q < 4) {
            float4 v = ((const float4*)(esh + (size_t)(e0 + e) * SH_DIM))[q];
            h = (short4v){(short)f2bf(v.x), (short)f2bf(v.y), (short)f2bf(v.z), (short)f2bf(v.w)};
        }
        *(short4v*)(sSH + ((e * 128 + q * 8) ^ ((e & 7) << 4))) = h;
    }
    if (tid < 64) {                                         // alpha_mean per edge
        float s = 0.f;
        #pragma unroll
        for (int h = 0; h < H_HEADS; ++h)
            s += __expf(a_buf[(size_t)(e0 + tid) * H_HEADS + h] - funmap(cmax[h])) / csum[h];
        amL[tid] = s * (1.0f / H_HEADS);
    }
    __syncthreads();

    const int lane = tid & 63, w = tid >> 6;
    const int rowBase = w * 16;
    const int l15 = lane & 15;
    f32x4 sc[8], xw[8], sw[8];

    zero8(sc);                                              // h1 = silu(ea@fc1+b1)
    mm_acc<1, 8, 128>(sEA, rowBase, lane, frags + FR_FC1, sc);
    store_rows_silu<256>(sH1, rowBase, lane, sc, b1);

    zero8(sc);                                              // h2 = silu(h1@fc2+b2)
    mm_acc<4, 8, 256>(sH1, rowBase, lane, frags + FR_FC2, sc);
    store_rows_silu<256>(sH2, rowBase, lane, sc, b2);

    zero8(sc);                                              // scale = h2@fc3+b3
    mm_acc<4, 8, 256>(sH2, rowBase, lane, frags + FR_FC3, sc);
    #pragma unroll
    for (int ct = 0; ct < 8; ++ct) sc[ct] += b3[ct * 16 + l15];

    zero8(xw);                                              // xw = x_src@W_node
    mm_acc<4, 8, 256>(sXS, rowBase, lane, frags + FR_WND, xw);

    zero8(sw);                                              // sw = edge_sh@W_sh
    mm_acc<1, 8, 128>(sSH, rowBase, lane, frags + FR_WSH, sw);

    // msg = silu(xw*scale + sw) * alpha_mean, packed-bf16 atomic scatter
    #pragma unroll
    for (int r = 0; r < 4; ++r) {
        const int row = rowBase + ((lane >> 4) * 4) + r;
        const float am = amL[row];
        const unsigned long long abase =
            (unsigned long long)(aggB) + (unsigned long long)didL[row] * (DIM * 2);
        #pragma unroll
        for (int cp = 0; cp < 4; ++cp) {
            const float m0 = silu(xw[2*cp][r]   * sc[2*cp][r]   + sw[2*cp][r])   * am;
            const float m1 = silu(xw[2*cp+1][r] * sc[2*cp+1][r] + sw[2*cp+1][r]) * am;
            const unsigned u  = (unsigned)f2bf(m0) | ((unsigned)f2bf(m1) << 16);
            const unsigned un = __shfl_xor(u, 1);
            if (!(lane & 1)) {
                const unsigned p0 = (u & 0xFFFFu) | (un << 16);          // (f, f+1) for ct=2cp
                const unsigned p1 = (u >> 16) | (un & 0xFFFF0000u);      // (f, f+1) for ct=2cp+1
                const unsigned long long a0 = abase + (unsigned)((2*cp*16 + l15) * 2);
                const unsigned long long a1 = abase + (unsigned)(((2*cp+1)*16 + l15) * 2);
                asm volatile("global_atomic_pk_add_bf16 %0, %1, off" :: "v"(a0), "v"(p0) : "memory");
                asm volatile("global_atomic_pk_add_bf16 %0, %1, off" :: "v"(a1), "v"(p1) : "memory");
            }
        }
    }
}

// ---------------------------------------------------------------------------
// K4: out = LayerNorm(node_features + agg @ W_out), agg is bf16
// ---------------------------------------------------------------------------
#define K4_NB 16

__global__ __launch_bounds__(256, 2) void k4_out(
    const float* __restrict__ nodef, const unsigned short* __restrict__ aggB,
    const float* __restrict__ W_out, float* __restrict__ outp)
{
    __shared__ float aggL[K4_NB * 132];
    __shared__ float outL[K4_NB * 144];
    const int tid = threadIdx.x;
    const int n0  = blockIdx.x * K4_NB;

    for (int idx = tid; idx < K4_NB * 16; idx += 256) {
        const int nl = idx >> 4, q = idx & 15;
        uint4 v = ((const uint4*)(aggB))[(size_t)(n0 + nl) * 16 + q];
        float* dstp = aggL + nl * 132 + q * 8;
        dstp[0] = bf2f((unsigned short)(v.x & 0xFFFF)); dstp[1] = bf2f((unsigned short)(v.x >> 16));
        dstp[2] = bf2f((unsigned short)(v.y & 0xFFFF)); dstp[3] = bf2f((unsigned short)(v.y >> 16));
        dstp[4] = bf2f((unsigned short)(v.z & 0xFFFF)); dstp[5] = bf2f((unsigned short)(v.z >> 16));
        dstp[6] = bf2f((unsigned short)(v.w & 0xFFFF)); dstp[7] = bf2f((unsigned short)(v.w >> 16));
    }
    __syncthreads();

    const int f = tid & 127, ng = tid >> 7;
    float acc[8];
    #pragma unroll
    for (int j = 0; j < 8; ++j) acc[j] = nodef[(size_t)(n0 + ng * 8 + j) * DIM + f];
    #pragma unroll 4
    for (int k = 0; k < DIM; ++k) {
        const float wv = W_out[(size_t)k * DIM + f];
        #pragma unroll
        for (int j = 0; j < 8; ++j) acc[j] += aggL[(ng * 8 + j) * 132 + k] * wv;
    }
    #pragma unroll
    for (int j = 0; j < 8; ++j) outL[(ng * 8 + j) * 144 + f] = acc[j];
    __syncthreads();

    const int node = tid >> 4, l16 = tid & 15;
    float v[8];
    float s = 0.f;
    #pragma unroll
    for (int j = 0; j < 8; ++j) { v[j] = outL[node * 144 + l16 + j * 16]; s += v[j]; }
    #pragma unroll
    for (int m = 1; m < 16; m <<= 1) s += __shfl_xor(s, m);
    const float mu = s * (1.0f / DIM);
    float vs = 0.f;
    #pragma unroll
    for (int j = 0; j < 8; ++j) { const float d = v[j] - mu; vs += d * d; }
    #pragma unroll
    for (int m = 1; m < 16; m <<= 1) vs += __shfl_xor(vs, m);
    const float rstd = rsqrtf(vs * (1.0f / DIM) + LN_EPS);
    #pragma unroll
    for (int j = 0; j < 8; ++j)
        outp[(size_t)(n0 + node) * DIM + l16 + j * 16] = (v[j] - mu) * rstd;
}

// ---------------------------------------------------------------------------
extern "C" void kernel_launch(void* const* d_in, const int* in_sizes, int n_in,
                              void* d_out, int out_size, void* d_ws, size_t ws_size,
                              hipStream_t stream)
{
    const float* nodef  = (const float*)d_in[0];
    const float* eattr  = (const float*)d_in[1];
    const float* esh    = (const float*)d_in[2];
    const float* W_node = (const float*)d_in[3];
    const float* fc1    = (const float*)d_in[4];
    const float* b1     = (const float*)d_in[5];
    const float* fc2    = (const float*)d_in[6];
    const float* b2     = (const float*)d_in[7];
    const float* fc3    = (const float*)d_in[8];
    const float* b3     = (const float*)d_in[9];
    const float* W_sh   = (const float*)d_in[10];
    const float* aW1    = (const float*)d_in[11];
    const float* ab1    = (const float*)d_in[12];
    const float* aW2    = (const float*)d_in[13];
    const float* ab2    = (const float*)d_in[14];
    const float* aW3    = (const float*)d_in[15];
    const float* ab3    = (const float*)d_in[16];
    const float* W_out  = (const float*)d_in[17];
    const int*   eidx   = (const int*)d_in[18];
    const int* srcp = eidx;
    const int* dstp = eidx + N_EDGES;

    float* ws = (float*)d_ws;
    unsigned short* aggB = (unsigned short*)ws;              // bf16 [N][128]
    unsigned int* cmax = (unsigned int*)(ws + 3200000);
    float* csum  = ws + 3200008;
    float* a_buf = ws + 3200016;                             // f32 [E][8]
    short8* frags = (short8*)(ws + 9600016);                 // 16B-aligned
    float* outp = (float*)d_out;

    k_prep    <<<47, 256, 0, stream>>>(fc1, fc2, fc3, W_node, W_sh, aW1, aW2, aW3, frags);
    k0_init   <<<2048, 256, 0, stream>>>((float*)aggB, cmax, csum);
    k1_logits <<<N_EDGES / 64, 256, 0, stream>>>(nodef, eattr, ab1, ab2, ab3, frags,
                                                 srcp, dstp, a_buf, cmax);
    k2_expsum <<<1024, 256, 0, stream>>>(a_buf, cmax, csum);
    k3_message<<<N_EDGES / 64, 256, 0, stream>>>(nodef, eattr, esh, b1, b2, b3, frags,
                                                 srcp, dstp, a_buf, cmax, csum, aggB);
    k4_out    <<<N_NODES / K4_NB, 256, 0, stream>>>(nodef, aggB, W_out, outp);
}

// Round 3
// 945.424 us; speedup vs baseline: 5.2921x; 1.2159x over previous
//
#include <hip/hip_runtime.h>
#include <math.h>

// Problem constants (fixed by the reference)
#define N_NODES 50000
#define N_EDGES 800000
#define DIM     128
#define SDIM    64
#define SH_DIM  16
#define EA_DIM  32
#define FC_DIM  128
#define H_HEADS 8
#define AIN_DIM 160   // 2*SD + EA
#define LN_EPS  1e-5f

typedef __attribute__((ext_vector_type(8))) short short8;   // 8 bf16 = one MFMA A/B fragment
typedef __attribute__((ext_vector_type(4))) short short4v;
typedef __attribute__((ext_vector_type(4))) float f32x4;

// Weight-fragment buffer layout (units of short8 = 16B fragments)
#define FR_FC1 0       // K=32  -> 1*8*64
#define FR_FC2 512     // K=128 -> 4*8*64
#define FR_FC3 2560
#define FR_WND 4608
#define FR_WSH 6656    // K=16 padded to 32
#define FR_AW1 7168    // K=160 -> 5*8*64
#define FR_AW2 9728
#define FR_AW3 11776   // K=128, N=8 (1 col tile) -> 4*1*64
#define FR_TOTAL 12032

__device__ __forceinline__ float silu(float x) {
    // fast: x * rcp(1+exp(-x)); v_rcp_f32 is ~1 ULP, fine for bf16-bound paths
    return x * __builtin_amdgcn_rcpf(1.0f + __expf(-x));
}

__device__ __forceinline__ unsigned short f2bf(float x) {     // RNE fp32->bf16
    unsigned u = __float_as_uint(x);
    return (unsigned short)((u + 0x7FFFu + ((u >> 16) & 1u)) >> 16);
}
__device__ __forceinline__ float bf2f(unsigned short h) { return __uint_as_float(((unsigned)h) << 16); }

__device__ __forceinline__ unsigned int fmap(float f) {
    unsigned int b = __float_as_uint(f);
    return (b & 0x80000000u) ? ~b : (b | 0x80000000u);
}
__device__ __forceinline__ float funmap(unsigned int u) {
    return (u & 0x80000000u) ? __uint_as_float(u & 0x7FFFFFFFu) : __uint_as_float(~u);
}

// ---------------------------------------------------------------------------
// mm_acc: per-wave MFMA GEMM over a 16-row LDS activation tile.
// A-frag: lane reads act[rowBase + (lane&15)][ks*32 + (lane>>4)*8 .. +7] (bf16,
// XOR-swizzled). B-frag: fragment-linear bf16 weights in global (L2-hot).
// ---------------------------------------------------------------------------
template<int KSTEPS, int NT, int STRIDE>
__device__ __forceinline__ void mm_acc(const char* aBase, int rowBase, int lane,
                                       const short8* __restrict__ bfrag, f32x4* acc)
{
    const int row  = rowBase + (lane & 15);
    const int swz  = (row & 7) << 4;
    const int rb   = row * STRIDE;
    const int koff = (lane >> 4) << 4;
    #pragma unroll
    for (int ks = 0; ks < KSTEPS; ++ks) {
        short8 a = *(const short8*)(aBase + ((rb + ks * 64 + koff) ^ swz));
        #pragma unroll
        for (int ct = 0; ct < NT; ++ct) {
            short8 b = bfrag[(ks * NT + ct) * 64 + lane];
            acc[ct] = __builtin_amdgcn_mfma_f32_16x16x32_bf16(a, b, acc[ct], 0, 0, 0);
        }
    }
}

// Store 8 col-tiles of a D-tile (col=lane&15, row=(lane>>4)*4+r) to swizzled
// bf16 LDS, adding bias and applying silu.
template<int STRIDE>
__device__ __forceinline__ void store_rows_silu(char* base, int rowBase, int lane,
                                                const f32x4* acc, const float* __restrict__ bias)
{
    const int l15  = lane & 15;
    const int col2 = l15 * 2;
    #pragma unroll
    for (int ct = 0; ct < 8; ++ct) {
        const float bv = bias[ct * 16 + l15];
        #pragma unroll
        for (int r = 0; r < 4; ++r) {
            const int row = rowBase + ((lane >> 4) * 4) + r;
            const float v = silu(acc[ct][r] + bv);
            const int off = (row * STRIDE + ct * 32 + col2) ^ ((row & 7) << 4);
            *(short*)(base + off) = (short)f2bf(v);
        }
    }
}

__device__ __forceinline__ void zero8(f32x4* a) {
    #pragma unroll
    for (int i = 0; i < 8; ++i) a[i] = (f32x4){0.f, 0.f, 0.f, 0.f};
}

// ---------------------------------------------------------------------------
// k_prep: convert all weight matrices to transposed bf16 fragment layout.
// frag[(ks*NT+ct)*64 + lane][i] = W[ks*32 + (lane>>4)*8 + i][ct*16 + (lane&15)]
// ---------------------------------------------------------------------------
__global__ void k_prep(const float* __restrict__ fc1, const float* __restrict__ fc2,
                       const float* __restrict__ fc3, const float* __restrict__ W_node,
                       const float* __restrict__ W_sh, const float* __restrict__ aW1,
                       const float* __restrict__ aW2, const float* __restrict__ aW3,
                       short8* __restrict__ frags)
{
    const int gid = blockIdx.x * 256 + threadIdx.x;   // exactly 12032 threads
    const float* src; int Ksrc, Nsrc, Nld, NT, base;
    if (gid < 2560) {
        if (gid < 512)  { src = fc1;  Ksrc = 32;  Nsrc = 128; Nld = 128; NT = 8; base = FR_FC1; }
        else            { src = fc2;  Ksrc = 128; Nsrc = 128; Nld = 128; NT = 8; base = FR_FC2; }
    } else if (gid < 6656) {
        if (gid < 4608) { src = fc3;    Ksrc = 128; Nsrc = 128; Nld = 128; NT = 8; base = FR_FC3; }
        else            { src = W_node; Ksrc = 128; Nsrc = 128; Nld = 128; NT = 8; base = FR_WND; }
    } else if (gid < 9728) {
        if (gid < 7168) { src = W_sh; Ksrc = 16;  Nsrc = 128; Nld = 128; NT = 8; base = FR_WSH; }
        else            { src = aW1;  Ksrc = 160; Nsrc = 128; Nld = 128; NT = 8; base = FR_AW1; }
    } else {
        if (gid < 11776){ src = aW2;  Ksrc = 128; Nsrc = 128; Nld = 128; NT = 8; base = FR_AW2; }
        else            { src = aW3;  Ksrc = 128; Nsrc = 8;   Nld = 8;   NT = 1; base = FR_AW3; }
    }
    const int local = gid - base;
    const int lane = local & 63;
    const int tmp  = local >> 6;
    const int ct   = tmp % NT;
    const int ks   = tmp / NT;
    const int col  = ct * 16 + (lane & 15);
    const int k0   = ks * 32 + ((lane >> 4) << 3);
    unsigned short o[8];
    #pragma unroll
    for (int i = 0; i < 8; ++i) {
        const int k = k0 + i;
        const float v = (k < Ksrc && col < Nsrc) ? src[(size_t)k * Nld + col] : 0.f;
        o[i] = f2bf(v);
    }
    unsigned a = (unsigned)o[0] | ((unsigned)o[1] << 16);
    unsigned b = (unsigned)o[2] | ((unsigned)o[3] << 16);
    unsigned c = (unsigned)o[4] | ((unsigned)o[5] << 16);
    unsigned d = (unsigned)o[6] | ((unsigned)o[7] << 16);
    ((uint4*)frags)[gid] = make_uint4(a, b, c, d);
}

__global__ void k0_init(float* __restrict__ aggz, unsigned int* __restrict__ cmax,
                        float* __restrict__ csum)
{
    const int total = N_NODES * (DIM / 2);   // bf16 agg = 3.2M dwords
    for (int i = blockIdx.x * blockDim.x + threadIdx.x; i < total;
         i += gridDim.x * blockDim.x)
        aggz[i] = 0.0f;
    if (blockIdx.x == 0 && threadIdx.x < H_HEADS) {
        cmax[threadIdx.x] = fmap(-3.0e38f);
        csum[threadIdx.x] = 0.0f;
    }
}

// ---------------------------------------------------------------------------
// K1: attention logits via MFMA. 64 edges/block, 4 waves x 16 edges.
// LDS: sAIN[64*512] + sG1[64*256]; g2 aliases sAIN (dead after layer 1).
// 48.8 KB -> 3 blocks/CU.
// ---------------------------------------------------------------------------
__global__ __launch_bounds__(256, 2) void k1_logits(
    const float* __restrict__ nodef, const float* __restrict__ eattr,
    const float* __restrict__ ab1, const float* __restrict__ ab2,
    const float* __restrict__ ab3,
    const short8* __restrict__ frags,
    const int* __restrict__ srcp, const int* __restrict__ dstp,
    float* __restrict__ a_out, unsigned int* __restrict__ cmax)
{
    __shared__ __align__(16) char sBuf[64 * 512 + 64 * 256];   // 48 KB
    char* sAIN = sBuf;              // [64][256] bf16 stride 512, swizzled
    char* sG1  = sBuf + 64 * 512;   // [64][128] bf16 stride 256
    char* sG2  = sBuf;              // alias: sAIN dead after layer 1
    __shared__ int sid[64], did[64];
    __shared__ float wmaxL[32];

    const int tid = threadIdx.x;
    const int e0  = blockIdx.x * 64;

    if (tid < 64)            sid[tid]      = srcp[e0 + tid];
    else if (tid < 128)      did[tid - 64] = dstp[e0 + tid - 64];
    __syncthreads();

    // stage alpha_in = [x_src[:64], x_dst[:64], edge_attr] as bf16, swizzled
    for (int idx = tid; idx < 64 * 40; idx += 256) {
        const int e = idx / 40, q = idx - e * 40;
        float4 v; int k;
        if (q < 16)      { v = ((const float4*)(nodef + (size_t)sid[e] * DIM))[q];      k = q * 4; }
        else if (q < 32) { v = ((const float4*)(nodef + (size_t)did[e] * DIM))[q - 16]; k = 64 + (q - 16) * 4; }
        else             { v = ((const float4*)(eattr + (size_t)(e0 + e) * EA_DIM))[q - 32]; k = 128 + (q - 32) * 4; }
        short4v h = {(short)f2bf(v.x), (short)f2bf(v.y), (short)f2bf(v.z), (short)f2bf(v.w)};
        *(short4v*)(sAIN + ((e * 512 + k * 2) ^ ((e & 7) << 4))) = h;
    }
    __syncthreads();

    const int lane = tid & 63, w = tid >> 6;
    const int rowBase = w * 16;
    f32x4 g[8];

    zero8(g);
    mm_acc<5, 8, 512>(sAIN, rowBase, lane, frags + FR_AW1, g);
    store_rows_silu<256>(sG1, rowBase, lane, g, ab1);
    __syncthreads();                      // all sAIN reads done; sG1 complete

    zero8(g);
    mm_acc<4, 8, 256>(sG1, rowBase, lane, frags + FR_AW2, g);
    store_rows_silu<256>(sG2, rowBase, lane, g, ab2);   // writes into sAIN alias
    __syncthreads();

    f32x4 p = {0.f, 0.f, 0.f, 0.f};
    mm_acc<4, 1, 256>(sG2, rowBase, lane, frags + FR_AW3, &p);

    const int h = lane & 15;
    float vmax = -3.0e38f;
    if (h < H_HEADS) {
        const float ab = ab3[h];
        #pragma unroll
        for (int r = 0; r < 4; ++r) {
            const int row = rowBase + ((lane >> 4) * 4) + r;
            const float v = p[r] + ab;
            a_out[(size_t)(e0 + row) * H_HEADS + h] = v;
            vmax = fmaxf(vmax, v);
        }
    }
    vmax = fmaxf(vmax, __shfl_xor(vmax, 16));
    vmax = fmaxf(vmax, __shfl_xor(vmax, 32));
    if (lane < 8) wmaxL[w * 8 + lane] = vmax;
    __syncthreads();
    if (tid < 8) {
        const float m = fmaxf(fmaxf(wmaxL[tid], wmaxL[8 + tid]),
                              fmaxf(wmaxL[16 + tid], wmaxL[24 + tid]));
        atomicMax(&cmax[tid], fmap(m));
    }
}

// ---------------------------------------------------------------------------
// K2: per-head sum of exp(a - max)
// ---------------------------------------------------------------------------
__global__ void k2_expsum(const float* __restrict__ a_buf,
                          const unsigned int* __restrict__ cmax,
                          float* __restrict__ csum)
{
    __shared__ float partial[4][8];
    const int tid = threadIdx.x;
    const int h   = tid & 7;
    const float M = funmap(cmax[h]);
    float s = 0.f;
    const int total = N_EDGES * H_HEADS;
    const int stride = gridDim.x * 256;
    for (int i = blockIdx.x * 256 + tid; i < total; i += stride)
        s += __expf(a_buf[i] - M);
    s += __shfl_xor(s, 8);
    s += __shfl_xor(s, 16);
    s += __shfl_xor(s, 32);
    const int wave = tid >> 6, lane = tid & 63;
    if (lane < 8) partial[wave][lane] = s;
    __syncthreads();
    if (tid < 8) {
        float t = partial[0][tid] + partial[1][tid] + partial[2][tid] + partial[3][tid];
        atomicAdd(&csum[tid], t);
    }
}

// ---------------------------------------------------------------------------
// K3: message path via MFMA + packed-bf16 scatter atomics.
// 64 edges/block, 4 waves x 16 edges.
// LDS 49.2 KB (sH2 aliases sEA+sSH) -> 3 blocks/CU.
// Phase order: stage | sw,h1 | h2(->alias) | sc,xw,epilogue
// ---------------------------------------------------------------------------
__global__ __launch_bounds__(256, 2) void k3_message(
    const float* __restrict__ nodef, const float* __restrict__ eattr,
    const float* __restrict__ esh,
    const float* __restrict__ b1, const float* __restrict__ b2,
    const float* __restrict__ b3,
    const short8* __restrict__ frags,
    const int* __restrict__ srcp, const int* __restrict__ dstp,
    const float* __restrict__ a_buf, const unsigned int* __restrict__ cmax,
    const float* __restrict__ csum,
    unsigned short* __restrict__ aggB)
{
    __shared__ __align__(16) char sBuf[49152];
    char* sXS = sBuf;            // [64][128] bf16 stride 256 (16 KB)
    char* sEA = sBuf + 16384;    // [64][ 64] bf16 stride 128 ( 8 KB)
    char* sSH = sBuf + 24576;    // [64][ 64] bf16 stride 128 ( 8 KB, hi 32 cols zero)
    char* sH1 = sBuf + 32768;    // [64][128] bf16 stride 256 (16 KB)
    char* sH2 = sBuf + 16384;    // alias sEA+sSH after phase 2 (16 KB, stride 256)
    __shared__ float amL[64];
    __shared__ int sidL[64], didL[64];

    const int tid = threadIdx.x;
    const int e0  = blockIdx.x * 64;

    if (tid < 64)       sidL[tid]      = srcp[e0 + tid];
    else if (tid < 128) didL[tid - 64] = dstp[e0 + tid - 64];
    __syncthreads();

    for (int idx = tid; idx < 64 * 32; idx += 256) {        // x_src
        const int e = idx >> 5, q = idx & 31;
        float4 v = ((const float4*)(nodef + (size_t)sidL[e] * DIM))[q];
        short4v h = {(short)f2bf(v.x), (short)f2bf(v.y), (short)f2bf(v.z), (short)f2bf(v.w)};
        *(short4v*)(sXS + ((e * 256 + q * 8) ^ ((e & 7) << 4))) = h;
    }
    for (int idx = tid; idx < 64 * 8; idx += 256) {         // edge_attr
        const int e = idx >> 3, q = idx & 7;
        float4 v = ((const float4*)(eattr + (size_t)(e0 + e) * EA_DIM))[q];
        short4v h = {(short)f2bf(v.x), (short)f2bf(v.y), (short)f2bf(v.z), (short)f2bf(v.w)};
        *(short4v*)(sEA + ((e * 128 + q * 8) ^ ((e & 7) << 4))) = h;
    }
    for (int idx = tid; idx < 64 * 8; idx += 256) {         // edge_sh (zero-padded K 16->32)
        const int e = idx >> 3, q = idx & 7;
        short4v h = {0, 0, 0, 0};
        if (q < 4) {
            float4 v = ((const float4*)(esh + (size_t)(e0 + e) * SH_DIM))[q];
            h = (short4v){(short)f2bf(v.x), (short)f2bf(v.y), (short)f2bf(v.z), (short)f2bf(v.w)};
        }
        *(short4v*)(sSH + ((e * 128 + q * 8) ^ ((e & 7) << 4))) = h;
    }
    if (tid < 64) {                                         // alpha_mean per edge
        float s = 0.f;
        #pragma unroll
        for (int h = 0; h < H_HEADS; ++h)
            s += __expf(a_buf[(size_t)(e0 + tid) * H_HEADS + h] - funmap(cmax[h])) / csum[h];
        amL[tid] = s * (1.0f / H_HEADS);
    }
    __syncthreads();

    const int lane = tid & 63, w = tid >> 6;
    const int rowBase = w * 16;
    const int l15 = lane & 15;
    f32x4 sc[8], xw[8], sw[8];

    // phase 2: sw (reads sSH) and h1 (reads sEA -> writes sH1)
    zero8(sw);                                              // sw = edge_sh@W_sh
    mm_acc<1, 8, 128>(sSH, rowBase, lane, frags + FR_WSH, sw);

    zero8(sc);                                              // h1 = silu(ea@fc1+b1)
    mm_acc<1, 8, 128>(sEA, rowBase, lane, frags + FR_FC1, sc);
    store_rows_silu<256>(sH1, rowBase, lane, sc, b1);
    __syncthreads();   // sEA/sSH reads done; sH1 complete

    // phase 3: h2 = silu(h1@fc2+b2) -> sH2 (aliases sEA+sSH)
    zero8(sc);
    mm_acc<4, 8, 256>(sH1, rowBase, lane, frags + FR_FC2, sc);
    store_rows_silu<256>(sH2, rowBase, lane, sc, b2);
    __syncthreads();

    // phase 4: scale = h2@fc3+b3 ; xw = x_src@W_node
    zero8(sc);
    mm_acc<4, 8, 256>(sH2, rowBase, lane, frags + FR_FC3, sc);
    #pragma unroll
    for (int ct = 0; ct < 8; ++ct) sc[ct] += b3[ct * 16 + l15];

    zero8(xw);
    mm_acc<4, 8, 256>(sXS, rowBase, lane, frags + FR_WND, xw);

    // msg = silu(xw*scale + sw) * alpha_mean, packed-bf16 atomic scatter
    #pragma unroll
    for (int r = 0; r < 4; ++r) {
        const int row = rowBase + ((lane >> 4) * 4) + r;
        const float am = amL[row];
        const unsigned long long abase =
            (unsigned long long)(aggB) + (unsigned long long)didL[row] * (DIM * 2);
        #pragma unroll
        for (int cp = 0; cp < 4; ++cp) {
            const float m0 = silu(xw[2*cp][r]   * sc[2*cp][r]   + sw[2*cp][r])   * am;
            const float m1 = silu(xw[2*cp+1][r] * sc[2*cp+1][r] + sw[2*cp+1][r]) * am;
            const unsigned u  = (unsigned)f2bf(m0) | ((unsigned)f2bf(m1) << 16);
            const unsigned un = __shfl_xor(u, 1);
            if (!(lane & 1)) {
                const unsigned p0 = (u & 0xFFFFu) | (un << 16);          // (f, f+1) for ct=2cp
                const unsigned p1 = (u >> 16) | (un & 0xFFFF0000u);      // (f, f+1) for ct=2cp+1
                const unsigned long long a0 = abase + (unsigned)((2*cp*16 + l15) * 2);
                const unsigned long long a1 = abase + (unsigned)(((2*cp+1)*16 + l15) * 2);
                asm volatile("global_atomic_pk_add_bf16 %0, %1, off" :: "v"(a0), "v"(p0) : "memory");
                asm volatile("global_atomic_pk_add_bf16 %0, %1, off" :: "v"(a1), "v"(p1) : "memory");
            }
        }
    }
}

// ---------------------------------------------------------------------------
// K4: out = LayerNorm(node_features + agg @ W_out), agg is bf16
// ---------------------------------------------------------------------------
#define K4_NB 16

__global__ __launch_bounds__(256, 2) void k4_out(
    const float* __restrict__ nodef, const unsigned short* __restrict__ aggB,
    const float* __restrict__ W_out, float* __restrict__ outp)
{
    __shared__ float aggL[K4_NB * 132];
    __shared__ float outL[K4_NB * 144];
    const int tid = threadIdx.x;
    const int n0  = blockIdx.x * K4_NB;

    for (int idx = tid; idx < K4_NB * 16; idx += 256) {
        const int nl = idx >> 4, q = idx & 15;
        uint4 v = ((const uint4*)(aggB))[(size_t)(n0 + nl) * 16 + q];
        float* dstp = aggL + nl * 132 + q * 8;
        dstp[0] = bf2f((unsigned short)(v.x & 0xFFFF)); dstp[1] = bf2f((unsigned short)(v.x >> 16));
        dstp[2] = bf2f((unsigned short)(v.y & 0xFFFF)); dstp[3] = bf2f((unsigned short)(v.y >> 16));
        dstp[4] = bf2f((unsigned short)(v.z & 0xFFFF)); dstp[5] = bf2f((unsigned short)(v.z >> 16));
        dstp[6] = bf2f((unsigned short)(v.w & 0xFFFF)); dstp[7] = bf2f((unsigned short)(v.w >> 16));
    }
    __syncthreads();

    const int f = tid & 127, ng = tid >> 7;
    float acc[8];
    #pragma unroll
    for (int j = 0; j < 8; ++j) acc[j] = nodef[(size_t)(n0 + ng * 8 + j) * DIM + f];
    #pragma unroll 4
    for (int k = 0; k < DIM; ++k) {
        const float wv = W_out[(size_t)k * DIM + f];
        #pragma unroll
        for (int j = 0; j < 8; ++j) acc[j] += aggL[(ng * 8 + j) * 132 + k] * wv;
    }
    #pragma unroll
    for (int j = 0; j < 8; ++j) outL[(ng * 8 + j) * 144 + f] = acc[j];
    __syncthreads();

    const int node = tid >> 4, l16 = tid & 15;
    float v[8];
    float s = 0.f;
    #pragma unroll
    for (int j = 0; j < 8; ++j) { v[j] = outL[node * 144 + l16 + j * 16]; s += v[j]; }
    #pragma unroll
    for (int m = 1; m < 16; m <<= 1) s += __shfl_xor(s, m);
    const float mu = s * (1.0f / DIM);
    float vs = 0.f;
    #pragma unroll
    for (int j = 0; j < 8; ++j) { const float d = v[j] - mu; vs += d * d; }
    #pragma unroll
    for (int m = 1; m < 16; m <<= 1) vs += __shfl_xor(vs, m);
    const float rstd = rsqrtf(vs * (1.0f / DIM) + LN_EPS);
    #pragma unroll
    for (int j = 0; j < 8; ++j)
        outp[(size_t)(n0 + node) * DIM + l16 + j * 16] = (v[j] - mu) * rstd;
}

// ---------------------------------------------------------------------------
extern "C" void kernel_launch(void* const* d_in, const int* in_sizes, int n_in,
                              void* d_out, int out_size, void* d_ws, size_t ws_size,
                              hipStream_t stream)
{
    const float* nodef  = (const float*)d_in[0];
    const float* eattr  = (const float*)d_in[1];
    const float* esh    = (const float*)d_in[2];
    const float* W_node = (const float*)d_in[3];
    const float* fc1    = (const float*)d_in[4];
    const float* b1     = (const float*)d_in[5];
    const float* fc2    = (const float*)d_in[6];
    const float* b2     = (const float*)d_in[7];
    const float* fc3    = (const float*)d_in[8];
    const float* b3     = (const float*)d_in[9];
    const float* W_sh   = (const float*)d_in[10];
    const float* aW1    = (const float*)d_in[11];
    const float* ab1    = (const float*)d_in[12];
    const float* aW2    = (const float*)d_in[13];
    const float* ab2    = (const float*)d_in[14];
    const float* aW3    = (const float*)d_in[15];
    const float* ab3    = (const float*)d_in[16];
    const float* W_out  = (const float*)d_in[17];
    const int*   eidx   = (const int*)d_in[18];
    const int* srcp = eidx;
    const int* dstp = eidx + N_EDGES;

    float* ws = (float*)d_ws;
    unsigned short* aggB = (unsigned short*)ws;              // bf16 [N][128]
    unsigned int* cmax = (unsigned int*)(ws + 3200000);
    float* csum  = ws + 3200008;
    float* a_buf = ws + 3200016;                             // f32 [E][8]
    short8* frags = (short8*)(ws + 9600016);                 // 16B-aligned
    float* outp = (float*)d_out;

    k_prep    <<<47, 256, 0, stream>>>(fc1, fc2, fc3, W_node, W_sh, aW1, aW2, aW3, frags);
    k0_init   <<<2048, 256, 0, stream>>>((float*)aggB, cmax, csum);
    k1_logits <<<N_EDGES / 64, 256, 0, stream>>>(nodef, eattr, ab1, ab2, ab3, frags,
                                                 srcp, dstp, a_buf, cmax);
    k2_expsum <<<1024, 256, 0, stream>>>(a_buf, cmax, csum);
    k3_message<<<N_EDGES / 64, 256, 0, stream>>>(nodef, eattr, esh, b1, b2, b3, frags,
                                                 srcp, dstp, a_buf, cmax, csum, aggB);
    k4_out    <<<N_NODES / K4_NB, 256, 0, stream>>>(nodef, aggB, W_out, outp);
}

// Round 4
// 868.503 us; speedup vs baseline: 5.7608x; 1.0886x over previous
//
#include <hip/hip_runtime.h>
#include <math.h>

// Problem constants (fixed by the reference)
#define N_NODES 50000
#define N_EDGES 800000
#define DIM     128
#define SDIM    64
#define SH_DIM  16
#define EA_DIM  32
#define FC_DIM  128
#define H_HEADS 8
#define AIN_DIM 160   // 2*SD + EA
#define LN_EPS  1e-5f

typedef __attribute__((ext_vector_type(8))) short short8;   // 8 bf16 = one MFMA A/B fragment
typedef __attribute__((ext_vector_type(4))) short short4v;
typedef __attribute__((ext_vector_type(4))) float f32x4;

// Weight-fragment buffer layout (units of short8 = 16B fragments)
#define FR_FC1 0       // K=32  -> 1*8*64
#define FR_FC2 512     // K=128 -> 4*8*64
#define FR_FC3 2560
#define FR_WND 4608
#define FR_WSH 6656    // K=16 padded to 32
#define FR_AW1 7168    // K=160 -> 5*8*64
#define FR_AW2 9728
#define FR_AW3 11776   // K=128, N=8 (1 col tile) -> 4*1*64
#define FR_TOTAL 12032

// ws layout (floats):
//   aggB   bf16[N][128]       : [0, 3,200,000)
//   cmax   8 x uint           : [3,200,000, 3,200,008)
//   csum   8 x f32            : [3,200,008, 3,200,016)
//   a_bufB bf16[E][8]         : [3,200,016, 6,400,016)
//   frags  12032 x 16B        : [6,400,016, 6,448,144)
//   nodefB bf16[N][128]       : [6,448,144, 9,648,144)
// total 38.6 MB (same as rounds 2-3)

__device__ __forceinline__ float silu(float x) {
    return x * __builtin_amdgcn_rcpf(1.0f + __expf(-x));
}

__device__ __forceinline__ unsigned short f2bf(float x) {     // RNE fp32->bf16
    unsigned u = __float_as_uint(x);
    return (unsigned short)((u + 0x7FFFu + ((u >> 16) & 1u)) >> 16);
}
__device__ __forceinline__ float bf2f(unsigned short h) { return __uint_as_float(((unsigned)h) << 16); }

__device__ __forceinline__ unsigned int fmap(float f) {
    unsigned int b = __float_as_uint(f);
    return (b & 0x80000000u) ? ~b : (b | 0x80000000u);
}
__device__ __forceinline__ float funmap(unsigned int u) {
    return (u & 0x80000000u) ? __uint_as_float(u & 0x7FFFFFFFu) : __uint_as_float(~u);
}

// ---------------------------------------------------------------------------
// mm_col: column-partitioned per-wave GEMM. The wave computes ALL 64 rows of
// the block's tile for its 2 owned col-tiles (ct0, ct0+1). A-frags from
// XOR-swizzled bf16 LDS; B-frags fragment-linear in global (L2-hot), loaded
// once per (ks,ct) and reused across 4 row-steps.
// ---------------------------------------------------------------------------
template<int KSTEPS, int STRIDE>
__device__ __forceinline__ void mm_col(const char* aBase, int lane, int ct0,
                                       const short8* __restrict__ bfrag, f32x4 (*acc)[2])
{
    const int l15  = lane & 15;
    const int koff = (lane >> 4) << 4;
    #pragma unroll
    for (int ks = 0; ks < KSTEPS; ++ks) {
        const short8 b0 = bfrag[(ks * 8 + ct0) * 64 + lane];
        const short8 b1 = bfrag[(ks * 8 + ct0 + 1) * 64 + lane];
        #pragma unroll
        for (int rs = 0; rs < 4; ++rs) {
            const int row = rs * 16 + l15;
            const short8 a = *(const short8*)(aBase + ((row * STRIDE + ks * 64 + koff) ^ ((row & 7) << 4)));
            acc[rs][0] = __builtin_amdgcn_mfma_f32_16x16x32_bf16(a, b0, acc[rs][0], 0, 0, 0);
            acc[rs][1] = __builtin_amdgcn_mfma_f32_16x16x32_bf16(a, b1, acc[rs][1], 0, 0, 0);
        }
    }
}

// row-partitioned variant (kept for K1 layer 3, N=8 single col-tile)
template<int KSTEPS, int NT, int STRIDE>
__device__ __forceinline__ void mm_acc(const char* aBase, int rowBase, int lane,
                                       const short8* __restrict__ bfrag, f32x4* acc)
{
    const int row  = rowBase + (lane & 15);
    const int swz  = (row & 7) << 4;
    const int rb   = row * STRIDE;
    const int koff = (lane >> 4) << 4;
    #pragma unroll
    for (int ks = 0; ks < KSTEPS; ++ks) {
        short8 a = *(const short8*)(aBase + ((rb + ks * 64 + koff) ^ swz));
        #pragma unroll
        for (int ct = 0; ct < NT; ++ct) {
            short8 b = bfrag[(ks * NT + ct) * 64 + lane];
            acc[ct] = __builtin_amdgcn_mfma_f32_16x16x32_bf16(a, b, acc[ct], 0, 0, 0);
        }
    }
}

// Store the wave's 2 col-tiles (all 64 rows) to swizzled bf16 LDS with bias+silu.
template<int STRIDE>
__device__ __forceinline__ void store_col_silu(char* base, int lane, int ct0,
                                               f32x4 (*acc)[2], const float* __restrict__ bias)
{
    const int l15  = lane & 15;
    const float bv0 = bias[ct0 * 16 + l15];
    const float bv1 = bias[ct0 * 16 + 16 + l15];
    #pragma unroll
    for (int rs = 0; rs < 4; ++rs) {
        #pragma unroll
        for (int r = 0; r < 4; ++r) {
            const int row = rs * 16 + ((lane >> 4) << 2) + r;
            const int swz = (row & 7) << 4;
            const float v0 = silu(acc[rs][0][r] + bv0);
            const float v1 = silu(acc[rs][1][r] + bv1);
            *(short*)(base + ((row * STRIDE + ct0 * 32 + l15 * 2) ^ swz))      = (short)f2bf(v0);
            *(short*)(base + ((row * STRIDE + ct0 * 32 + 32 + l15 * 2) ^ swz)) = (short)f2bf(v1);
        }
    }
}

__device__ __forceinline__ void zerocol(f32x4 (*a)[2]) {
    #pragma unroll
    for (int i = 0; i < 4; ++i) {
        a[i][0] = (f32x4){0.f, 0.f, 0.f, 0.f};
        a[i][1] = (f32x4){0.f, 0.f, 0.f, 0.f};
    }
}

// ---------------------------------------------------------------------------
// k_prep: weights -> transposed bf16 fragment layout.
// frag[(ks*NT+ct)*64 + lane][i] = W[ks*32 + (lane>>4)*8 + i][ct*16 + (lane&15)]
// ---------------------------------------------------------------------------
__global__ void k_prep(const float* __restrict__ fc1, const float* __restrict__ fc2,
                       const float* __restrict__ fc3, const float* __restrict__ W_node,
                       const float* __restrict__ W_sh, const float* __restrict__ aW1,
                       const float* __restrict__ aW2, const float* __restrict__ aW3,
                       short8* __restrict__ frags)
{
    const int gid = blockIdx.x * 256 + threadIdx.x;   // exactly 12032 threads
    const float* src; int Ksrc, Nsrc, Nld, NT, base;
    if (gid < 2560) {
        if (gid < 512)  { src = fc1;  Ksrc = 32;  Nsrc = 128; Nld = 128; NT = 8; base = FR_FC1; }
        else            { src = fc2;  Ksrc = 128; Nsrc = 128; Nld = 128; NT = 8; base = FR_FC2; }
    } else if (gid < 6656) {
        if (gid < 4608) { src = fc3;    Ksrc = 128; Nsrc = 128; Nld = 128; NT = 8; base = FR_FC3; }
        else            { src = W_node; Ksrc = 128; Nsrc = 128; Nld = 128; NT = 8; base = FR_WND; }
    } else if (gid < 9728) {
        if (gid < 7168) { src = W_sh; Ksrc = 16;  Nsrc = 128; Nld = 128; NT = 8; base = FR_WSH; }
        else            { src = aW1;  Ksrc = 160; Nsrc = 128; Nld = 128; NT = 8; base = FR_AW1; }
    } else {
        if (gid < 11776){ src = aW2;  Ksrc = 128; Nsrc = 128; Nld = 128; NT = 8; base = FR_AW2; }
        else            { src = aW3;  Ksrc = 128; Nsrc = 8;   Nld = 8;   NT = 1; base = FR_AW3; }
    }
    const int local = gid - base;
    const int lane = local & 63;
    const int tmp  = local >> 6;
    const int ct   = tmp % NT;
    const int ks   = tmp / NT;
    const int col  = ct * 16 + (lane & 15);
    const int k0   = ks * 32 + ((lane >> 4) << 3);
    unsigned short o[8];
    #pragma unroll
    for (int i = 0; i < 8; ++i) {
        const int k = k0 + i;
        const float v = (k < Ksrc && col < Nsrc) ? src[(size_t)k * Nld + col] : 0.f;
        o[i] = f2bf(v);
    }
    unsigned a = (unsigned)o[0] | ((unsigned)o[1] << 16);
    unsigned b = (unsigned)o[2] | ((unsigned)o[3] << 16);
    unsigned c = (unsigned)o[4] | ((unsigned)o[5] << 16);
    unsigned d = (unsigned)o[6] | ((unsigned)o[7] << 16);
    ((uint4*)frags)[gid] = make_uint4(a, b, c, d);
}

// k_prep2: node_features fp32 -> bf16 [N][128]
__global__ void k_prep2(const float* __restrict__ nodef, unsigned short* __restrict__ nodefB)
{
    const int i = blockIdx.x * 256 + threadIdx.x;     // 1.6M float4s exactly
    float4 v = ((const float4*)nodef)[i];
    short4v h = {(short)f2bf(v.x), (short)f2bf(v.y), (short)f2bf(v.z), (short)f2bf(v.w)};
    ((short4v*)nodefB)[i] = h;
}

__global__ void k0_init(float* __restrict__ aggz, unsigned int* __restrict__ cmax,
                        float* __restrict__ csum)
{
    const int total = N_NODES * (DIM / 2);   // bf16 agg = 3.2M dwords
    for (int i = blockIdx.x * blockDim.x + threadIdx.x; i < total;
         i += gridDim.x * blockDim.x)
        aggz[i] = 0.0f;
    if (blockIdx.x == 0 && threadIdx.x < H_HEADS) {
        cmax[threadIdx.x] = fmap(-3.0e38f);
        csum[threadIdx.x] = 0.0f;
    }
}

// ---------------------------------------------------------------------------
// K1: attention logits via MFMA, column-partitioned waves.
// 64 edges/block; wave w owns col-tiles {2w,2w+1} for layers 1-2,
// rows [16w,16w+16) for layer 3 (N=8).
// ---------------------------------------------------------------------------
__global__ __launch_bounds__(256, 2) void k1_logits(
    const unsigned short* __restrict__ nodefB, const float* __restrict__ eattr,
    const float* __restrict__ ab1, const float* __restrict__ ab2,
    const float* __restrict__ ab3,
    const short8* __restrict__ frags,
    const int* __restrict__ srcp, const int* __restrict__ dstp,
    unsigned short* __restrict__ a_outB, unsigned int* __restrict__ cmax)
{
    __shared__ __align__(16) char sBuf[64 * 512 + 64 * 256];   // 48 KB
    char* sAIN = sBuf;              // [64][256] bf16 stride 512, swizzled (cols 0-159 used)
    char* sG1  = sBuf + 64 * 512;   // [64][128] bf16 stride 256
    char* sG2  = sBuf;              // alias: sAIN dead after layer 1
    __shared__ int sid[64], did[64];
    __shared__ float wmaxL[32];

    const int tid = threadIdx.x;
    const int e0  = blockIdx.x * 64;

    if (tid < 64)            sid[tid]      = srcp[e0 + tid];
    else if (tid < 128)      did[tid - 64] = dstp[e0 + tid - 64];
    __syncthreads();

    // stage alpha_in = [x_src[:64], x_dst[:64], edge_attr]; x from bf16 table
    for (int idx = tid; idx < 64 * 24; idx += 256) {
        const int e = idx / 24, q = idx - e * 24;
        if (q < 16) {
            const int node = (q < 8) ? sid[e] : did[e];
            const int qq = q & 7;
            short8 v = ((const short8*)(nodefB + (size_t)node * DIM))[qq];
            const int k = (q < 8 ? 0 : 64) + qq * 8;
            *(short8*)(sAIN + ((e * 512 + k * 2) ^ ((e & 7) << 4))) = v;
        } else {
            float4 v = ((const float4*)(eattr + (size_t)(e0 + e) * EA_DIM))[q - 16];
            short4v h = {(short)f2bf(v.x), (short)f2bf(v.y), (short)f2bf(v.z), (short)f2bf(v.w)};
            const int k = 128 + (q - 16) * 4;
            *(short4v*)(sAIN + ((e * 512 + k * 2) ^ ((e & 7) << 4))) = h;
        }
    }
    __syncthreads();

    const int lane = tid & 63, w = tid >> 6;
    const int ct0 = w * 2;
    f32x4 acc[4][2];

    zerocol(acc);                                   // g1 = silu(ain@aW1+ab1)
    mm_col<5, 512>(sAIN, lane, ct0, frags + FR_AW1, acc);
    store_col_silu<256>(sG1, lane, ct0, acc, ab1);
    __syncthreads();                                // sAIN reads done; sG1 complete

    zerocol(acc);                                   // g2 = silu(g1@aW2+ab2) -> alias
    mm_col<4, 256>(sG1, lane, ct0, frags + FR_AW2, acc);
    store_col_silu<256>(sG2, lane, ct0, acc, ab2);
    __syncthreads();

    f32x4 p = {0.f, 0.f, 0.f, 0.f};                 // a = g2@aW3+ab3 (N=8)
    mm_acc<4, 1, 256>(sG2, w * 16, lane, frags + FR_AW3, &p);

    const int h = lane & 15;
    float vmax = -3.0e38f;
    if (h < H_HEADS) {
        const float ab = ab3[h];
        #pragma unroll
        for (int r = 0; r < 4; ++r) {
            const int row = w * 16 + ((lane >> 4) << 2) + r;
            const unsigned short bv = f2bf(p[r] + ab);
            a_outB[(size_t)(e0 + row) * H_HEADS + h] = bv;
            vmax = fmaxf(vmax, bf2f(bv));           // max over ROUNDED values
        }
    }
    vmax = fmaxf(vmax, __shfl_xor(vmax, 16));
    vmax = fmaxf(vmax, __shfl_xor(vmax, 32));
    if (lane < 8) wmaxL[w * 8 + lane] = vmax;
    __syncthreads();
    if (tid < 8) {
        const float m = fmaxf(fmaxf(wmaxL[tid], wmaxL[8 + tid]),
                              fmaxf(wmaxL[16 + tid], wmaxL[24 + tid]));
        atomicMax(&cmax[tid], fmap(m));
    }
}

// ---------------------------------------------------------------------------
// K2: per-head sum of exp(a - max); a_buf is bf16 pairs
// ---------------------------------------------------------------------------
__global__ void k2_expsum(const unsigned* __restrict__ a_bufB,
                          const unsigned int* __restrict__ cmax,
                          float* __restrict__ csum)
{
    __shared__ float partial[4][8];
    const int tid = threadIdx.x;
    const int p   = tid & 3;                        // head pair (2p, 2p+1)
    const float M0 = funmap(cmax[2 * p]);
    const float M1 = funmap(cmax[2 * p + 1]);
    float s0 = 0.f, s1 = 0.f;
    const int total = N_EDGES * 4;                  // uints
    const int stride = gridDim.x * 256;             // multiple of 4 -> p invariant
    for (int i = blockIdx.x * 256 + tid; i < total; i += stride) {
        const unsigned v = a_bufB[i];
        s0 += __expf(bf2f((unsigned short)(v & 0xFFFFu)) - M0);
        s1 += __expf(bf2f((unsigned short)(v >> 16)) - M1);
    }
    s0 += __shfl_xor(s0, 4);  s1 += __shfl_xor(s1, 4);
    s0 += __shfl_xor(s0, 8);  s1 += __shfl_xor(s1, 8);
    s0 += __shfl_xor(s0, 16); s1 += __shfl_xor(s1, 16);
    s0 += __shfl_xor(s0, 32); s1 += __shfl_xor(s1, 32);
    const int wave = tid >> 6, lane = tid & 63;
    if (lane < 4) { partial[wave][lane * 2] = s0; partial[wave][lane * 2 + 1] = s1; }
    __syncthreads();
    if (tid < 8) {
        float t = partial[0][tid] + partial[1][tid] + partial[2][tid] + partial[3][tid];
        atomicAdd(&csum[tid], t);
    }
}

// ---------------------------------------------------------------------------
// K3: message path via MFMA (column-partitioned) + packed-bf16 scatter atomics.
// 64 edges/block; wave w owns col-tiles {2w, 2w+1} of all outputs.
// LDS 48 KB (sH2 aliases sEA+sSH) -> 3 blocks/CU.
// ---------------------------------------------------------------------------
__global__ __launch_bounds__(256, 2) void k3_message(
    const unsigned short* __restrict__ nodefB, const float* __restrict__ eattr,
    const float* __restrict__ esh,
    const float* __restrict__ b1, const float* __restrict__ b2,
    const float* __restrict__ b3,
    const short8* __restrict__ frags,
    const int* __restrict__ srcp, const int* __restrict__ dstp,
    const unsigned short* __restrict__ a_bufB, const unsigned int* __restrict__ cmax,
    const float* __restrict__ csum,
    unsigned short* __restrict__ aggB)
{
    __shared__ __align__(16) char sBuf[49152];
    char* sXS = sBuf;            // [64][128] bf16 stride 256 (16 KB)
    char* sEA = sBuf + 16384;    // [64][ 64] bf16 stride 128 ( 8 KB)
    char* sSH = sBuf + 24576;    // [64][ 64] bf16 stride 128 ( 8 KB, hi 32 cols zero)
    char* sH1 = sBuf + 32768;    // [64][128] bf16 stride 256 (16 KB)
    char* sH2 = sBuf + 16384;    // alias sEA+sSH after phase 2
    __shared__ float amL[64];
    __shared__ int sidL[64], didL[64];

    const int tid = threadIdx.x;
    const int e0  = blockIdx.x * 64;

    if (tid < 64)       sidL[tid]      = srcp[e0 + tid];
    else if (tid < 128) didL[tid - 64] = dstp[e0 + tid - 64];
    __syncthreads();

    for (int idx = tid; idx < 64 * 16; idx += 256) {        // x_src (bf16 table)
        const int e = idx >> 4, q = idx & 15;
        short8 v = ((const short8*)(nodefB + (size_t)sidL[e] * DIM))[q];
        *(short8*)(sXS + ((e * 256 + q * 16) ^ ((e & 7) << 4))) = v;
    }
    for (int idx = tid; idx < 64 * 8; idx += 256) {         // edge_attr
        const int e = idx >> 3, q = idx & 7;
        float4 v = ((const float4*)(eattr + (size_t)(e0 + e) * EA_DIM))[q];
        short4v h = {(short)f2bf(v.x), (short)f2bf(v.y), (short)f2bf(v.z), (short)f2bf(v.w)};
        *(short4v*)(sEA + ((e * 128 + q * 8) ^ ((e & 7) << 4))) = h;
    }
    for (int idx = tid; idx < 64 * 8; idx += 256) {         // edge_sh (zero-padded K 16->32)
        const int e = idx >> 3, q = idx & 7;
        short4v h = {0, 0, 0, 0};
        if (q < 4) {
            float4 v = ((const float4*)(esh + (size_t)(e0 + e) * SH_DIM))[q];
            h = (short4v){(short)f2bf(v.x), (short)f2bf(v.y), (short)f2bf(v.z), (short)f2bf(v.w)};
        }
        *(short4v*)(sSH + ((e * 128 + q * 8) ^ ((e & 7) << 4))) = h;
    }
    if (tid < 64) {                                         // alpha_mean per edge
        uint4 v = ((const uint4*)a_bufB)[e0 + tid];
        const unsigned short* pv = (const unsigned short*)&v;
        float s = 0.f;
        #pragma unroll
        for (int h = 0; h < H_HEADS; ++h)
            s += __expf(bf2f(pv[h]) - funmap(cmax[h])) * __builtin_amdgcn_rcpf(csum[h]);
        amL[tid] = s * (1.0f / H_HEADS);
    }
    __syncthreads();

    const int lane = tid & 63, w = tid >> 6;
    const int ct0 = w * 2, l15 = lane & 15;
    f32x4 sw[4][2], sc[4][2], xw[4][2];

    // phase 2: sw (reads sSH, HELD in regs across phases) and h1 -> sH1
    zerocol(sw);
    mm_col<1, 128>(sSH, lane, ct0, frags + FR_WSH, sw);
    zerocol(sc);
    mm_col<1, 128>(sEA, lane, ct0, frags + FR_FC1, sc);
    store_col_silu<256>(sH1, lane, ct0, sc, b1);
    __syncthreads();   // sEA/sSH reads done; sH1 complete

    // phase 3: h2 = silu(h1@fc2+b2) -> sH2 (aliases sEA+sSH)
    zerocol(sc);
    mm_col<4, 256>(sH1, lane, ct0, frags + FR_FC2, sc);
    store_col_silu<256>(sH2, lane, ct0, sc, b2);
    __syncthreads();

    // phase 4: scale = h2@fc3+b3 ; xw = x_src@W_node
    zerocol(sc);
    mm_col<4, 256>(sH2, lane, ct0, frags + FR_FC3, sc);
    zerocol(xw);
    mm_col<4, 256>(sXS, lane, ct0, frags + FR_WND, xw);

    const float bv0 = b3[ct0 * 16 + l15];
    const float bv1 = b3[ct0 * 16 + 16 + l15];

    // msg = silu(xw*scale + sw) * alpha_mean, packed-bf16 atomic scatter
    #pragma unroll
    for (int rs = 0; rs < 4; ++rs) {
        #pragma unroll
        for (int r = 0; r < 4; ++r) {
            const int row = rs * 16 + ((lane >> 4) << 2) + r;
            const float am = amL[row];
            const float m0 = silu(xw[rs][0][r] * (sc[rs][0][r] + bv0) + sw[rs][0][r]) * am;
            const float m1 = silu(xw[rs][1][r] * (sc[rs][1][r] + bv1) + sw[rs][1][r]) * am;
            const unsigned u  = (unsigned)f2bf(m0) | ((unsigned)f2bf(m1) << 16);
            const unsigned un = __shfl_xor(u, 1);
            if (!(lane & 1)) {
                const unsigned p0 = (u & 0xFFFFu) | (un << 16);          // adjacent cols, ct0
                const unsigned p1 = (u >> 16) | (un & 0xFFFF0000u);      // adjacent cols, ct0+1
                const unsigned long long abase =
                    (unsigned long long)aggB + (unsigned long long)didL[row] * (DIM * 2);
                const unsigned long long a0 = abase + (unsigned)((ct0 * 16 + l15) * 2);
                const unsigned long long a1 = abase + (unsigned)((ct0 * 16 + 16 + l15) * 2);
                asm volatile("global_atomic_pk_add_bf16 %0, %1, off" :: "v"(a0), "v"(p0) : "memory");
                asm volatile("global_atomic_pk_add_bf16 %0, %1, off" :: "v"(a1), "v"(p1) : "memory");
            }
        }
    }
}

// ---------------------------------------------------------------------------
// K4: out = LayerNorm(node_features + agg @ W_out), agg is bf16
// ---------------------------------------------------------------------------
#define K4_NB 16

__global__ __launch_bounds__(256, 2) void k4_out(
    const float* __restrict__ nodef, const unsigned short* __restrict__ aggB,
    const float* __restrict__ W_out, float* __restrict__ outp)
{
    __shared__ float aggL[K4_NB * 132];
    __shared__ float outL[K4_NB * 144];
    const int tid = threadIdx.x;
    const int n0  = blockIdx.x * K4_NB;

    for (int idx = tid; idx < K4_NB * 16; idx += 256) {
        const int nl = idx >> 4, q = idx & 15;
        uint4 v = ((const uint4*)(aggB))[(size_t)(n0 + nl) * 16 + q];
        float* dstp = aggL + nl * 132 + q * 8;
        dstp[0] = bf2f((unsigned short)(v.x & 0xFFFF)); dstp[1] = bf2f((unsigned short)(v.x >> 16));
        dstp[2] = bf2f((unsigned short)(v.y & 0xFFFF)); dstp[3] = bf2f((unsigned short)(v.y >> 16));
        dstp[4] = bf2f((unsigned short)(v.z & 0xFFFF)); dstp[5] = bf2f((unsigned short)(v.z >> 16));
        dstp[6] = bf2f((unsigned short)(v.w & 0xFFFF)); dstp[7] = bf2f((unsigned short)(v.w >> 16));
    }
    __syncthreads();

    const int f = tid & 127, ng = tid >> 7;
    float acc[8];
    #pragma unroll
    for (int j = 0; j < 8; ++j) acc[j] = nodef[(size_t)(n0 + ng * 8 + j) * DIM + f];
    #pragma unroll 4
    for (int k = 0; k < DIM; ++k) {
        const float wv = W_out[(size_t)k * DIM + f];
        #pragma unroll
        for (int j = 0; j < 8; ++j) acc[j] += aggL[(ng * 8 + j) * 132 + k] * wv;
    }
    #pragma unroll
    for (int j = 0; j < 8; ++j) outL[(ng * 8 + j) * 144 + f] = acc[j];
    __syncthreads();

    const int node = tid >> 4, l16 = tid & 15;
    float v[8];
    float s = 0.f;
    #pragma unroll
    for (int j = 0; j < 8; ++j) { v[j] = outL[node * 144 + l16 + j * 16]; s += v[j]; }
    #pragma unroll
    for (int m = 1; m < 16; m <<= 1) s += __shfl_xor(s, m);
    const float mu = s * (1.0f / DIM);
    float vs = 0.f;
    #pragma unroll
    for (int j = 0; j < 8; ++j) { const float d = v[j] - mu; vs += d * d; }
    #pragma unroll
    for (int m = 1; m < 16; m <<= 1) vs += __shfl_xor(vs, m);
    const float rstd = rsqrtf(vs * (1.0f / DIM) + LN_EPS);
    #pragma unroll
    for (int j = 0; j < 8; ++j)
        outp[(size_t)(n0 + node) * DIM + l16 + j * 16] = (v[j] - mu) * rstd;
}

// ---------------------------------------------------------------------------
extern "C" void kernel_launch(void* const* d_in, const int* in_sizes, int n_in,
                              void* d_out, int out_size, void* d_ws, size_t ws_size,
                              hipStream_t stream)
{
    const float* nodef  = (const float*)d_in[0];
    const float* eattr  = (const float*)d_in[1];
    const float* esh    = (const float*)d_in[2];
    const float* W_node = (const float*)d_in[3];
    const float* fc1    = (const float*)d_in[4];
    const float* b1     = (const float*)d_in[5];
    const float* fc2    = (const float*)d_in[6];
    const float* b2     = (const float*)d_in[7];
    const float* fc3    = (const float*)d_in[8];
    const float* b3     = (const float*)d_in[9];
    const float* W_sh   = (const float*)d_in[10];
    const float* aW1    = (const float*)d_in[11];
    const float* ab1    = (const float*)d_in[12];
    const float* aW2    = (const float*)d_in[13];
    const float* ab2    = (const float*)d_in[14];
    const float* aW3    = (const float*)d_in[15];
    const float* ab3    = (const float*)d_in[16];
    const float* W_out  = (const float*)d_in[17];
    const int*   eidx   = (const int*)d_in[18];
    const int* srcp = eidx;
    const int* dstp = eidx + N_EDGES;

    float* ws = (float*)d_ws;
    unsigned short* aggB  = (unsigned short*)ws;             // bf16 [N][128]
    unsigned int*   cmax  = (unsigned int*)(ws + 3200000);
    float*          csum  = ws + 3200008;
    unsigned short* a_bufB = (unsigned short*)(ws + 3200016);// bf16 [E][8]
    short8*         frags = (short8*)(ws + 6400016);         // 16B-aligned
    unsigned short* nodefB = (unsigned short*)(ws + 6448144);// bf16 [N][128]
    float* outp = (float*)d_out;

    k_prep    <<<47, 256, 0, stream>>>(fc1, fc2, fc3, W_node, W_sh, aW1, aW2, aW3, frags);
    k_prep2   <<<N_NODES * DIM / 4 / 256, 256, 0, stream>>>(nodef, nodefB);
    k0_init   <<<2048, 256, 0, stream>>>((float*)aggB, cmax, csum);
    k1_logits <<<N_EDGES / 64, 256, 0, stream>>>(nodefB, eattr, ab1, ab2, ab3, frags,
                                                 srcp, dstp, a_bufB, cmax);
    k2_expsum <<<1024, 256, 0, stream>>>((const unsigned*)a_bufB, cmax, csum);
    k3_message<<<N_EDGES / 64, 256, 0, stream>>>(nodefB, eattr, esh, b1, b2, b3, frags,
                                                 srcp, dstp, a_bufB, cmax, csum, aggB);
    k4_out    <<<N_NODES / K4_NB, 256, 0, stream>>>(nodef, aggB, W_out, outp);
}

// Round 6
// 822.071 us; speedup vs baseline: 6.0862x; 1.0565x over previous
//
#include <hip/hip_runtime.h>
#include <math.h>

// Problem constants (fixed by the reference)
#define N_NODES 50000
#define N_EDGES 800000
#define DIM     128
#define SDIM    64
#define SH_DIM  16
#define EA_DIM  32
#define FC_DIM  128
#define H_HEADS 8
#define LN_EPS  1e-5f

typedef __attribute__((ext_vector_type(8))) short short8;   // 8 bf16 = one MFMA A/B fragment
typedef __attribute__((ext_vector_type(4))) float f32x4;

// Weight-fragment buffer layout (units of short8 = 16B fragments)
#define FR_FC1   0       // fc1 K=32            -> 512
#define FR_FC2   512     // fc2 K=128           -> 2048
#define FR_FC3   2560    // fc3 K=128           -> 2048
#define FR_WND   4608    // W_node K=128        -> 2048 (used by kP_node only)
#define FR_WSH   6656    // W_sh K=16 pad 32    -> 512
#define FR_AW1EA 7168    // aW1 rows 128:160    -> 512
#define FR_AW1A  7680    // aW1 rows 0:64       -> 1024 (kP_node)
#define FR_AW1B  8704    // aW1 rows 64:128     -> 1024 (kP_node)
#define FR_AW2   9728    // aW2 K=128           -> 2048
#define FR_AW3   11776   // aW3 K=128 N=8       -> 256
#define FR_TOTAL 12032

// ws layout (floats):
//   aggB   bf16[N][128]  : [0, 3,200,000)
//   cmax   8 x uint      : [3,200,000, 3,200,008)
//   csum   8 x f32       : [3,200,008, 3,200,016)
//   a_bufB bf16[E][8]    : [3,200,016, 6,400,016)
//   frags  12032 x 16B   : [6,400,016, 6,448,144)
//   XWB    bf16[N][128]  : [6,448,144, 9,648,144)
//   P1B    bf16[N][128]  : [9,648,144, 12,848,144)
//   P2B    bf16[N][128]  : [12,848,144, 16,048,144)   total ~64.2 MB

__device__ __forceinline__ float silu(float x) {
    return x * __builtin_amdgcn_rcpf(1.0f + __expf(-x));
}
__device__ __forceinline__ unsigned short f2bf(float x) {     // RNE fp32->bf16
    unsigned u = __float_as_uint(x);
    return (unsigned short)((u + 0x7FFFu + ((u >> 16) & 1u)) >> 16);
}
__device__ __forceinline__ float bf2f(unsigned short h) { return __uint_as_float(((unsigned)h) << 16); }

__device__ __forceinline__ unsigned int fmap(float f) {
    unsigned int b = __float_as_uint(f);
    return (b & 0x80000000u) ? ~b : (b | 0x80000000u);
}
__device__ __forceinline__ float funmap(unsigned int u) {
    return (u & 0x80000000u) ? __uint_as_float(u & 0x7FFFFFFFu) : __uint_as_float(~u);
}
__device__ __forceinline__ uint4 pack8(float4 a, float4 b) {
    return make_uint4((unsigned)f2bf(a.x) | ((unsigned)f2bf(a.y) << 16),
                      (unsigned)f2bf(a.z) | ((unsigned)f2bf(a.w) << 16),
                      (unsigned)f2bf(b.x) | ((unsigned)f2bf(b.y) << 16),
                      (unsigned)f2bf(b.z) | ((unsigned)f2bf(b.w) << 16));
}
__device__ __forceinline__ unsigned addpk(unsigned a, unsigned b) {
    float lo = bf2f((unsigned short)(a & 0xFFFFu)) + bf2f((unsigned short)(b & 0xFFFFu));
    float hi = bf2f((unsigned short)(a >> 16))     + bf2f((unsigned short)(b >> 16));
    return (unsigned)f2bf(lo) | ((unsigned)f2bf(hi) << 16);
}

// ---------------------------------------------------------------------------
// mm_col: column-partitioned per-wave GEMM. Wave computes ALL 64 rows for its
// 2 owned col-tiles. A-frags from XOR-swizzled bf16 LDS; B-frags from global.
// ---------------------------------------------------------------------------
template<int KSTEPS, int STRIDE, int SWZM>
__device__ __forceinline__ void mm_col(const char* aBase, int lane, int ct0,
                                       const short8* __restrict__ bfrag, f32x4 (*acc)[2])
{
    const int l15  = lane & 15;
    const int koff = (lane >> 4) << 4;
    #pragma unroll
    for (int ks = 0; ks < KSTEPS; ++ks) {
        const short8 b0 = bfrag[(ks * 8 + ct0) * 64 + lane];
        const short8 b1 = bfrag[(ks * 8 + ct0 + 1) * 64 + lane];
        #pragma unroll
        for (int rs = 0; rs < 4; ++rs) {
            const int row = rs * 16 + l15;
            const short8 a = *(const short8*)(aBase +
                ((row * STRIDE + ks * 64 + koff) ^ ((row & SWZM) << 4)));
            acc[rs][0] = __builtin_amdgcn_mfma_f32_16x16x32_bf16(a, b0, acc[rs][0], 0, 0, 0);
            acc[rs][1] = __builtin_amdgcn_mfma_f32_16x16x32_bf16(a, b1, acc[rs][1], 0, 0, 0);
        }
    }
}

// row-partitioned variant (K1 layer 3, N=8 single col-tile)
template<int KSTEPS, int NT, int STRIDE>
__device__ __forceinline__ void mm_acc(const char* aBase, int rowBase, int lane,
                                       const short8* __restrict__ bfrag, f32x4* acc)
{
    const int row  = rowBase + (lane & 15);
    const int swz  = (row & 7) << 4;
    const int rb   = row * STRIDE;
    const int koff = (lane >> 4) << 4;
    #pragma unroll
    for (int ks = 0; ks < KSTEPS; ++ks) {
        short8 a = *(const short8*)(aBase + ((rb + ks * 64 + koff) ^ swz));
        #pragma unroll
        for (int ct = 0; ct < NT; ++ct) {
            short8 b = bfrag[(ks * NT + ct) * 64 + lane];
            acc[ct] = __builtin_amdgcn_mfma_f32_16x16x32_bf16(a, b, acc[ct], 0, 0, 0);
        }
    }
}

// Store wave's 2 col-tiles (64 rows) to swizzled bf16 LDS with bias+silu.
__device__ __forceinline__ void store_col_silu(char* base, int lane, int ct0,
                                               f32x4 (*acc)[2], const float* __restrict__ bias)
{
    const int l15  = lane & 15;
    const float bv0 = bias[ct0 * 16 + l15];
    const float bv1 = bias[ct0 * 16 + 16 + l15];
    #pragma unroll
    for (int rs = 0; rs < 4; ++rs) {
        #pragma unroll
        for (int r = 0; r < 4; ++r) {
            const int row = rs * 16 + ((lane >> 4) << 2) + r;
            const int swz = (row & 7) << 4;
            const float v0 = silu(acc[rs][0][r] + bv0);
            const float v1 = silu(acc[rs][1][r] + bv1);
            *(short*)(base + ((row * 256 + ct0 * 32 + l15 * 2) ^ swz))      = (short)f2bf(v0);
            *(short*)(base + ((row * 256 + ct0 * 32 + 32 + l15 * 2) ^ swz)) = (short)f2bf(v1);
        }
    }
}

// raw variant (no bias / no silu) for kP_node
__device__ __forceinline__ void store_col_raw(char* base, int lane, int ct0, f32x4 (*acc)[2])
{
    const int l15 = lane & 15;
    #pragma unroll
    for (int rs = 0; rs < 4; ++rs) {
        #pragma unroll
        for (int r = 0; r < 4; ++r) {
            const int row = rs * 16 + ((lane >> 4) << 2) + r;
            const int swz = (row & 7) << 4;
            *(short*)(base + ((row * 256 + ct0 * 32 + l15 * 2) ^ swz))      = (short)f2bf(acc[rs][0][r]);
            *(short*)(base + ((row * 256 + ct0 * 32 + 32 + l15 * 2) ^ swz)) = (short)f2bf(acc[rs][1][r]);
        }
    }
}

__device__ __forceinline__ void zerocol(f32x4 (*a)[2]) {
    #pragma unroll
    for (int i = 0; i < 4; ++i) {
        a[i][0] = (f32x4){0.f, 0.f, 0.f, 0.f};
        a[i][1] = (f32x4){0.f, 0.f, 0.f, 0.f};
    }
}

// ---------------------------------------------------------------------------
// k_prep: weights -> transposed bf16 fragment layout.
// frag[(ks*NT+ct)*64 + lane][i] = W[rowOff + ks*32 + (lane>>4)*8 + i][ct*16 + (lane&15)]
// ---------------------------------------------------------------------------
__global__ void k_prep(const float* __restrict__ fc1, const float* __restrict__ fc2,
                       const float* __restrict__ fc3, const float* __restrict__ W_node,
                       const float* __restrict__ W_sh, const float* __restrict__ aW1,
                       const float* __restrict__ aW2, const float* __restrict__ aW3,
                       uint4* __restrict__ frags)
{
    const int gid = blockIdx.x * 256 + threadIdx.x;   // exactly 12032 threads
    const float* src; int Ksrc = 128, Nsrc = 128, Nld = 128, NT = 8, base, rowOff = 0;
    if (gid < 4608) {
        if (gid < 512)        { src = fc1;  Ksrc = 32;  base = FR_FC1; }
        else if (gid < 2560)  { src = fc2;              base = FR_FC2; }
        else                  { src = fc3;              base = FR_FC3; }
    } else if (gid < 7168) {
        if (gid < 6656)       { src = W_node;           base = FR_WND; }
        else                  { src = W_sh; Ksrc = 16;  base = FR_WSH; }
    } else if (gid < 9728) {
        if (gid < 7680)       { src = aW1; Ksrc = 32; rowOff = 128; base = FR_AW1EA; }
        else if (gid < 8704)  { src = aW1; Ksrc = 64; rowOff = 0;   base = FR_AW1A; }
        else                  { src = aW1; Ksrc = 64; rowOff = 64;  base = FR_AW1B; }
    } else {
        if (gid < 11776)      { src = aW2;              base = FR_AW2; }
        else                  { src = aW3; Nsrc = 8; Nld = 8; NT = 1; base = FR_AW3; }
    }
    const int local = gid - base;
    const int lane = local & 63;
    const int tmp  = local >> 6;
    const int ct   = tmp % NT;
    const int ks   = tmp / NT;
    const int col  = ct * 16 + (lane & 15);
    const int k0   = ks * 32 + ((lane >> 4) << 3);
    unsigned short o[8];
    #pragma unroll
    for (int i = 0; i < 8; ++i) {
        const int k = k0 + i;
        const float v = (k < Ksrc && col < Nsrc) ? src[(size_t)(rowOff + k) * Nld + col] : 0.f;
        o[i] = f2bf(v);
    }
    frags[gid] = make_uint4((unsigned)o[0] | ((unsigned)o[1] << 16),
                            (unsigned)o[2] | ((unsigned)o[3] << 16),
                            (unsigned)o[4] | ((unsigned)o[5] << 16),
                            (unsigned)o[6] | ((unsigned)o[7] << 16));
}

// ---------------------------------------------------------------------------
// kP_node: dense node-level precompute (782 blocks x 64 rows):
//   XW = nodef @ W_node ; P1 = nodef[:,:64] @ aW1[0:64] ; P2 = nodef[:,:64] @ aW1[64:128]
// ---------------------------------------------------------------------------
__global__ __launch_bounds__(256, 2) void kP_node(
    const float* __restrict__ nodef, const short8* __restrict__ frags,
    uint4* __restrict__ XWB, uint4* __restrict__ P1B, uint4* __restrict__ P2B)
{
    __shared__ __align__(16) char sA[16384];
    __shared__ __align__(16) char sO[16384];
    const int tid = threadIdx.x;
    const int n0  = blockIdx.x * 64;

    #pragma unroll
    for (int i = 0; i < 4; ++i) {                      // stage 64 node rows, bf16 swizzled
        const int c = tid + 256 * i, r = c >> 4, q = c & 15;
        int idx = n0 + r; if (idx >= N_NODES) idx = N_NODES - 1;
        float4 a = ((const float4*)(nodef + (size_t)idx * DIM))[q * 2];
        float4 b = ((const float4*)(nodef + (size_t)idx * DIM))[q * 2 + 1];
        *(uint4*)(sA + ((r * 256 + q * 16) ^ ((r & 7) << 4))) = pack8(a, b);
    }
    __syncthreads();

    const int lane = tid & 63, wv = tid >> 6, ct0 = wv * 2;
    f32x4 acc[4][2];

    zerocol(acc); mm_col<4, 256, 7>(sA, lane, ct0, frags + FR_WND, acc);
    store_col_raw(sO, lane, ct0, acc);
    __syncthreads();
    #pragma unroll
    for (int i = 0; i < 4; ++i) {
        const int c = tid + 256 * i, r = c >> 4, q = c & 15;
        if (n0 + r < N_NODES)
            XWB[(size_t)(n0 + r) * 16 + q] = *(uint4*)(sO + ((r * 256 + q * 16) ^ ((r & 7) << 4)));
    }
    __syncthreads();

    zerocol(acc); mm_col<2, 256, 7>(sA, lane, ct0, frags + FR_AW1A, acc);
    store_col_raw(sO, lane, ct0, acc);
    __syncthreads();
    #pragma unroll
    for (int i = 0; i < 4; ++i) {
        const int c = tid + 256 * i, r = c >> 4, q = c & 15;
        if (n0 + r < N_NODES)
            P1B[(size_t)(n0 + r) * 16 + q] = *(uint4*)(sO + ((r * 256 + q * 16) ^ ((r & 7) << 4)));
    }
    __syncthreads();

    zerocol(acc); mm_col<2, 256, 7>(sA, lane, ct0, frags + FR_AW1B, acc);
    store_col_raw(sO, lane, ct0, acc);
    __syncthreads();
    #pragma unroll
    for (int i = 0; i < 4; ++i) {
        const int c = tid + 256 * i, r = c >> 4, q = c & 15;
        if (n0 + r < N_NODES)
            P2B[(size_t)(n0 + r) * 16 + q] = *(uint4*)(sO + ((r * 256 + q * 16) ^ ((r & 7) << 4)));
    }
}

__global__ void k0_init(float* __restrict__ aggz, unsigned int* __restrict__ cmax,
                        float* __restrict__ csum)
{
    const int total = N_NODES * (DIM / 2);   // bf16 agg = 3.2M dwords
    for (int i = blockIdx.x * blockDim.x + threadIdx.x; i < total;
         i += gridDim.x * blockDim.x)
        aggz[i] = 0.0f;
    if (blockIdx.x == 0 && threadIdx.x < H_HEADS) {
        cmax[threadIdx.x] = fmap(-3.0e38f);
        csum[threadIdx.x] = 0.0f;
    }
}

// ---------------------------------------------------------------------------
// K1: attention logits. g1 = silu(P1[src]+P2[dst] + EA@aW1ea + ab1);
// g2 = silu(g1@aW2+ab2); a = g2@aW3+ab3.  LDS exactly 32 KB.
// ---------------------------------------------------------------------------
__global__ __launch_bounds__(256, 4) void k1_logits(
    const float* __restrict__ eattr,
    const float* __restrict__ ab1, const float* __restrict__ ab2,
    const float* __restrict__ ab3,
    const short8* __restrict__ frags,
    const int* __restrict__ srcp, const int* __restrict__ dstp,
    const uint4* __restrict__ P1B, const uint4* __restrict__ P2B,
    unsigned short* __restrict__ a_outB, unsigned int* __restrict__ cmax)
{
    __shared__ __align__(16) char sBuf[32768];
    char* sG1 = sBuf;            // [64][256B] swz7 (written phase 2b)
    char* sEA = sBuf + 12288;    // [64][64B] swz3, aliases sG1 tail (dead by 2b)
    char* R2  = sBuf + 16384;    // sP -> sG2; [0,128) reused as wmaxL at the end
    float* wmaxL = (float*)R2;

    const int tid = threadIdx.x;
    const int e0  = blockIdx.x * 64;

    // phase 1: issue P1[src]+P2[dst] gathers to regs; stage sEA
    uint4 pa[4], pb[4];
    #pragma unroll
    for (int i = 0; i < 4; ++i) {
        const int c = tid + 256 * i, e = c >> 4, q = c & 15;
        const int s = srcp[e0 + e], d = dstp[e0 + e];
        pa[i] = P1B[(size_t)s * 16 + q];
        pb[i] = P2B[(size_t)d * 16 + q];
    }
    {
        const int e = tid >> 2, q = tid & 3;
        float4 a = ((const float4*)(eattr + (size_t)(e0 + e) * EA_DIM))[q * 2];
        float4 b = ((const float4*)(eattr + (size_t)(e0 + e) * EA_DIM))[q * 2 + 1];
        *(uint4*)(sEA + e * 64 + ((q * 16) ^ ((e & 3) << 4))) = pack8(a, b);
    }
    __syncthreads();

    const int lane = tid & 63, wv = tid >> 6, ct0 = wv * 2, l15 = lane & 15;
    f32x4 acc[4][2];

    // phase 2a: EA part of layer 1; write sP (= P1+P2 sums)
    zerocol(acc);
    mm_col<1, 64, 3>(sEA, lane, ct0, frags + FR_AW1EA, acc);
    #pragma unroll
    for (int i = 0; i < 4; ++i) {
        const int c = tid + 256 * i, e = c >> 4, q = c & 15;
        uint4 s;
        s.x = addpk(pa[i].x, pb[i].x); s.y = addpk(pa[i].y, pb[i].y);
        s.z = addpk(pa[i].z, pb[i].z); s.w = addpk(pa[i].w, pb[i].w);
        *(uint4*)(R2 + ((e * 256 + q * 16) ^ ((e & 7) << 4))) = s;
    }
    __syncthreads();

    // phase 2b: g1 = silu(accEA + ab1 + sP) -> sG1 (overwrites sEA tail)
    {
        const float bv0 = ab1[ct0 * 16 + l15];
        const float bv1 = ab1[ct0 * 16 + 16 + l15];
        const int c0 = ct0 * 32 + l15 * 2, c1 = c0 + 32;
        #pragma unroll
        for (int rs = 0; rs < 4; ++rs) {
            #pragma unroll
            for (int r = 0; r < 4; ++r) {
                const int row = rs * 16 + ((lane >> 4) << 2) + r;
                const int swz = (row & 7) << 4;
                const float p0 = bf2f(*(const unsigned short*)(R2 + ((row * 256 + c0) ^ swz)));
                const float p1 = bf2f(*(const unsigned short*)(R2 + ((row * 256 + c1) ^ swz)));
                const float v0 = silu(acc[rs][0][r] + bv0 + p0);
                const float v1 = silu(acc[rs][1][r] + bv1 + p1);
                *(short*)(sG1 + ((row * 256 + c0) ^ swz)) = (short)f2bf(v0);
                *(short*)(sG1 + ((row * 256 + c1) ^ swz)) = (short)f2bf(v1);
            }
        }
    }
    __syncthreads();

    // phase 3: g2 = silu(g1@aW2+ab2) -> R2 (sP dead)
    zerocol(acc);
    mm_col<4, 256, 7>(sG1, lane, ct0, frags + FR_AW2, acc);
    store_col_silu(R2, lane, ct0, acc, ab2);
    __syncthreads();

    // phase 4: a = g2@aW3+ab3 (N=8), logits + per-head max
    f32x4 p = {0.f, 0.f, 0.f, 0.f};
    mm_acc<4, 1, 256>(R2, wv * 16, lane, frags + FR_AW3, &p);
    __syncthreads();   // all R2 reads done before wmaxL aliases it

    const int h = l15;
    float vmax = -3.0e38f;
    if (h < H_HEADS) {
        const float ab = ab3[h];
        #pragma unroll
        for (int r = 0; r < 4; ++r) {
            const int row = wv * 16 + ((lane >> 4) << 2) + r;
            const unsigned short bv = f2bf(p[r] + ab);
            a_outB[(size_t)(e0 + row) * H_HEADS + h] = bv;
            vmax = fmaxf(vmax, bf2f(bv));           // max over ROUNDED values
        }
    }
    vmax = fmaxf(vmax, __shfl_xor(vmax, 16));
    vmax = fmaxf(vmax, __shfl_xor(vmax, 32));
    if (lane < 8) wmaxL[wv * 8 + lane] = vmax;
    __syncthreads();
    if (tid < 8) {
        const float m = fmaxf(fmaxf(wmaxL[tid], wmaxL[8 + tid]),
                              fmaxf(wmaxL[16 + tid], wmaxL[24 + tid]));
        atomicMax(&cmax[tid], fmap(m));
    }
}

// ---------------------------------------------------------------------------
// K2: per-head sum of exp(a - max); a_buf is bf16 pairs
// ---------------------------------------------------------------------------
__global__ void k2_expsum(const unsigned* __restrict__ a_bufB,
                          const unsigned int* __restrict__ cmax,
                          float* __restrict__ csum)
{
    __shared__ float partial[4][8];
    const int tid = threadIdx.x;
    const int p   = tid & 3;                        // head pair (2p, 2p+1)
    const float M0 = funmap(cmax[2 * p]);
    const float M1 = funmap(cmax[2 * p + 1]);
    float s0 = 0.f, s1 = 0.f;
    const int total = N_EDGES * 4;                  // uints
    const int stride = gridDim.x * 256;
    for (int i = blockIdx.x * 256 + tid; i < total; i += stride) {
        const unsigned v = a_bufB[i];
        s0 += __expf(bf2f((unsigned short)(v & 0xFFFFu)) - M0);
        s1 += __expf(bf2f((unsigned short)(v >> 16)) - M1);
    }
    s0 += __shfl_xor(s0, 4);  s1 += __shfl_xor(s1, 4);
    s0 += __shfl_xor(s0, 8);  s1 += __shfl_xor(s1, 8);
    s0 += __shfl_xor(s0, 16); s1 += __shfl_xor(s1, 16);
    s0 += __shfl_xor(s0, 32); s1 += __shfl_xor(s1, 32);
    const int wave = tid >> 6, lane = tid & 63;
    if (lane < 4) { partial[wave][lane * 2] = s0; partial[wave][lane * 2 + 1] = s1; }
    __syncthreads();
    if (tid < 8) {
        float t = partial[0][tid] + partial[1][tid] + partial[2][tid] + partial[3][tid];
        atomicAdd(&csum[tid], t);
    }
}

// ---------------------------------------------------------------------------
// K3: message path. xw gathered from precomputed XWB (issue-early/write-late);
// h1/h2/scale via MFMA; packed-bf16 atomic scatter. LDS 33 KB.
// ---------------------------------------------------------------------------
__global__ __launch_bounds__(256, 4) void k3_message(
    const float* __restrict__ eattr, const float* __restrict__ esh,
    const float* __restrict__ b1, const float* __restrict__ b2,
    const float* __restrict__ b3,
    const short8* __restrict__ frags,
    const int* __restrict__ srcp, const int* __restrict__ dstp,
    const unsigned short* __restrict__ a_bufB, const unsigned int* __restrict__ cmax,
    const float* __restrict__ csum,
    const uint4* __restrict__ XWB,
    unsigned short* __restrict__ aggB)
{
    __shared__ __align__(16) char sBuf[32768];
    char* R1 = sBuf;             // sH1 -> sXW
    char* R2 = sBuf + 16384;     // sEA [0,4K) + sSH [4K,8K) -> sH2
    __shared__ unsigned sMeta[64];   // (dst<<16) | bf16(alpha_mean)
    char* sEA = R2;
    char* sSH = R2 + 4096;

    const int tid = threadIdx.x;
    const int e0  = blockIdx.x * 64;

    // phase 0: stage edge_attr / edge_sh (bf16, swz3), meta
    {
        const int e = tid >> 2, q = tid & 3;
        float4 a = ((const float4*)(eattr + (size_t)(e0 + e) * EA_DIM))[q * 2];
        float4 b = ((const float4*)(eattr + (size_t)(e0 + e) * EA_DIM))[q * 2 + 1];
        *(uint4*)(sEA + e * 64 + ((q * 16) ^ ((e & 3) << 4))) = pack8(a, b);
        uint4 hz = make_uint4(0, 0, 0, 0);
        if (q < 2) {
            float4 c = ((const float4*)(esh + (size_t)(e0 + e) * SH_DIM))[q * 2];
            float4 d = ((const float4*)(esh + (size_t)(e0 + e) * SH_DIM))[q * 2 + 1];
            hz = pack8(c, d);
        }
        *(uint4*)(sSH + e * 64 + ((q * 16) ^ ((e & 3) << 4))) = hz;
    }
    if (tid < 64) {
        uint4 av = ((const uint4*)a_bufB)[e0 + tid];
        const unsigned short* pv = (const unsigned short*)&av;
        float s = 0.f;
        #pragma unroll
        for (int h = 0; h < H_HEADS; ++h)
            s += __expf(bf2f(pv[h]) - funmap(cmax[h])) * __builtin_amdgcn_rcpf(csum[h]);
        sMeta[tid] = ((unsigned)dstp[e0 + tid] << 16) | (unsigned)f2bf(s * (1.0f / H_HEADS));
    }
    __syncthreads();

    const int lane = tid & 63, wv = tid >> 6, ct0 = wv * 2, l15 = lane & 15;
    f32x4 sw[4][2], acc[4][2];

    // phase 1: sw = edge_sh@W_sh (regs); h1 = silu(ea@fc1+b1) -> sH1
    zerocol(sw);
    mm_col<1, 64, 3>(sSH, lane, ct0, frags + FR_WSH, sw);
    zerocol(acc);
    mm_col<1, 64, 3>(sEA, lane, ct0, frags + FR_FC1, acc);
    store_col_silu(R1, lane, ct0, acc, b1);
    __syncthreads();

    // phase 2: issue XW gather to regs; h2 = silu(h1@fc2+b2) -> sH2 (R2)
    uint4 xwc[4];
    #pragma unroll
    for (int i = 0; i < 4; ++i) {
        const int c = tid + 256 * i, e = c >> 4, q = c & 15;
        const int s = srcp[e0 + e];
        xwc[i] = XWB[(size_t)s * 16 + q];
    }
    zerocol(acc);
    mm_col<4, 256, 7>(R1, lane, ct0, frags + FR_FC2, acc);
    store_col_silu(R2, lane, ct0, acc, b2);
    __syncthreads();

    // phase 3: write sXW (R1, sH1 dead); scale = h2@fc3 -> acc
    #pragma unroll
    for (int i = 0; i < 4; ++i) {
        const int c = tid + 256 * i, e = c >> 4, q = c & 15;
        *(uint4*)(R1 + ((e * 256 + q * 16) ^ ((e & 7) << 4))) = xwc[i];
    }
    zerocol(acc);
    mm_col<4, 256, 7>(R2, lane, ct0, frags + FR_FC3, acc);
    __syncthreads();

    // phase 4: msg = silu(xw*(scale+b3) + sw) * alpha_mean; packed atomics
    const float bv0 = b3[ct0 * 16 + l15];
    const float bv1 = b3[ct0 * 16 + 16 + l15];
    const int c0 = ct0 * 32 + l15 * 2, c1 = c0 + 32;
    #pragma unroll
    for (int rs = 0; rs < 4; ++rs) {
        #pragma unroll
        for (int r = 0; r < 4; ++r) {
            const int row = rs * 16 + ((lane >> 4) << 2) + r;
            const int swz = (row & 7) << 4;
            const unsigned meta = sMeta[row];
            const float am = bf2f((unsigned short)(meta & 0xFFFFu));
            const float xw0 = bf2f(*(const unsigned short*)(R1 + ((row * 256 + c0) ^ swz)));
            const float xw1 = bf2f(*(const unsigned short*)(R1 + ((row * 256 + c1) ^ swz)));
            const float m0 = silu(xw0 * (acc[rs][0][r] + bv0) + sw[rs][0][r]) * am;
            const float m1 = silu(xw1 * (acc[rs][1][r] + bv1) + sw[rs][1][r]) * am;
            const unsigned u  = (unsigned)f2bf(m0) | ((unsigned)f2bf(m1) << 16);
            const unsigned un = __shfl_xor(u, 1);
            if (!(lane & 1)) {
                const unsigned p0 = (u & 0xFFFFu) | (un << 16);
                const unsigned p1 = (u >> 16) | (un & 0xFFFF0000u);
                const unsigned long long abase =
                    (unsigned long long)aggB + (unsigned long long)(meta >> 16) * (DIM * 2);
                const unsigned long long a0 = abase + (unsigned)((ct0 * 16 + l15) * 2);
                const unsigned long long a1 = abase + (unsigned)((ct0 * 16 + 16 + l15) * 2);
                asm volatile("global_atomic_pk_add_bf16 %0, %1, off" :: "v"(a0), "v"(p0) : "memory");
                asm volatile("global_atomic_pk_add_bf16 %0, %1, off" :: "v"(a1), "v"(p1) : "memory");
            }
        }
    }
}

// ---------------------------------------------------------------------------
// K4: out = LayerNorm(node_features + agg @ W_out), agg is bf16
// ---------------------------------------------------------------------------
#define K4_NB 16

__global__ __launch_bounds__(256, 2) void k4_out(
    const float* __restrict__ nodef, const unsigned short* __restrict__ aggB,
    const float* __restrict__ W_out, float* __restrict__ outp)
{
    __shared__ float aggL[K4_NB * 132];
    __shared__ float outL[K4_NB * 144];
    const int tid = threadIdx.x;
    const int n0  = blockIdx.x * K4_NB;

    for (int idx = tid; idx < K4_NB * 16; idx += 256) {
        const int nl = idx >> 4, q = idx & 15;
        uint4 v = ((const uint4*)(aggB))[(size_t)(n0 + nl) * 16 + q];
        float* dstp = aggL + nl * 132 + q * 8;
        dstp[0] = bf2f((unsigned short)(v.x & 0xFFFF)); dstp[1] = bf2f((unsigned short)(v.x >> 16));
        dstp[2] = bf2f((unsigned short)(v.y & 0xFFFF)); dstp[3] = bf2f((unsigned short)(v.y >> 16));
        dstp[4] = bf2f((unsigned short)(v.z & 0xFFFF)); dstp[5] = bf2f((unsigned short)(v.z >> 16));
        dstp[6] = bf2f((unsigned short)(v.w & 0xFFFF)); dstp[7] = bf2f((unsigned short)(v.w >> 16));
    }
    __syncthreads();

    const int f = tid & 127, ng = tid >> 7;
    float acc[8];
    #pragma unroll
    for (int j = 0; j < 8; ++j) acc[j] = nodef[(size_t)(n0 + ng * 8 + j) * DIM + f];
    #pragma unroll 4
    for (int k = 0; k < DIM; ++k) {
        const float wv = W_out[(size_t)k * DIM + f];
        #pragma unroll
        for (int j = 0; j < 8; ++j) acc[j] += aggL[(ng * 8 + j) * 132 + k] * wv;
    }
    #pragma unroll
    for (int j = 0; j < 8; ++j) outL[(ng * 8 + j) * 144 + f] = acc[j];
    __syncthreads();

    const int node = tid >> 4, l16 = tid & 15;
    float v[8];
    float s = 0.f;
    #pragma unroll
    for (int j = 0; j < 8; ++j) { v[j] = outL[node * 144 + l16 + j * 16]; s += v[j]; }
    #pragma unroll
    for (int m = 1; m < 16; m <<= 1) s += __shfl_xor(s, m);
    const float mu = s * (1.0f / DIM);
    float vs = 0.f;
    #pragma unroll
    for (int j = 0; j < 8; ++j) { const float d = v[j] - mu; vs += d * d; }
    #pragma unroll
    for (int m = 1; m < 16; m <<= 1) vs += __shfl_xor(vs, m);
    const float rstd = rsqrtf(vs * (1.0f / DIM) + LN_EPS);
    #pragma unroll
    for (int j = 0; j < 8; ++j)
        outp[(size_t)(n0 + node) * DIM + l16 + j * 16] = (v[j] - mu) * rstd;
}

// ---------------------------------------------------------------------------
extern "C" void kernel_launch(void* const* d_in, const int* in_sizes, int n_in,
                              void* d_out, int out_size, void* d_ws, size_t ws_size,
                              hipStream_t stream)
{
    const float* nodef  = (const float*)d_in[0];
    const float* eattr  = (const float*)d_in[1];
    const float* esh    = (const float*)d_in[2];
    const float* W_node = (const float*)d_in[3];
    const float* fc1    = (const float*)d_in[4];
    const float* b1     = (const float*)d_in[5];
    const float* fc2    = (const float*)d_in[6];
    const float* b2     = (const float*)d_in[7];
    const float* fc3    = (const float*)d_in[8];
    const float* b3     = (const float*)d_in[9];
    const float* W_sh   = (const float*)d_in[10];
    const float* aW1    = (const float*)d_in[11];
    const float* ab1    = (const float*)d_in[12];
    const float* aW2    = (const float*)d_in[13];
    const float* ab2    = (const float*)d_in[14];
    const float* aW3    = (const float*)d_in[15];
    const float* ab3    = (const float*)d_in[16];
    const float* W_out  = (const float*)d_in[17];
    const int*   eidx   = (const int*)d_in[18];
    const int* srcp = eidx;
    const int* dstp = eidx + N_EDGES;

    float* ws = (float*)d_ws;
    unsigned short* aggB   = (unsigned short*)ws;              // bf16 [N][128]
    unsigned int*   cmax   = (unsigned int*)(ws + 3200000);
    float*          csum   = ws + 3200008;
    unsigned short* a_bufB = (unsigned short*)(ws + 3200016);  // bf16 [E][8]
    uint4*          frags  = (uint4*)(ws + 6400016);           // 12032 x 16B
    uint4*          XWB    = (uint4*)(ws + 6448144);           // bf16 [N][128]
    uint4*          P1B    = (uint4*)(ws + 9648144);
    uint4*          P2B    = (uint4*)(ws + 12848144);
    float* outp = (float*)d_out;

    k_prep    <<<47, 256, 0, stream>>>(fc1, fc2, fc3, W_node, W_sh, aW1, aW2, aW3, frags);
    kP_node   <<<(N_NODES + 63) / 64, 256, 0, stream>>>(nodef, (const short8*)frags,
                                                        XWB, P1B, P2B);
    k0_init   <<<2048, 256, 0, stream>>>((float*)aggB, cmax, csum);
    k1_logits <<<N_EDGES / 64, 256, 0, stream>>>(eattr, ab1, ab2, ab3, (const short8*)frags,
                                                 srcp, dstp, P1B, P2B, a_bufB, cmax);
    k2_expsum <<<1024, 256, 0, stream>>>((const unsigned*)a_bufB, cmax, csum);
    k3_message<<<N_EDGES / 64, 256, 0, stream>>>(eattr, esh, b1, b2, b3, (const short8*)frags,
                                                 srcp, dstp, a_bufB, cmax, csum, XWB, aggB);
    k4_out    <<<N_NODES / K4_NB, 256, 0, stream>>>(nodef, aggB, W_out, outp);
}